// Round 1
// baseline (525.092 us; speedup 1.0000x reference)
//
#include <hip/hip_runtime.h>

typedef __attribute__((ext_vector_type(8))) short bf16x8;
typedef __attribute__((ext_vector_type(16))) float f32x16;

static __device__ __forceinline__ unsigned short f2bf(float x) {
  unsigned int u = __float_as_uint(x);
  return (unsigned short)((u + 0x7FFFu + ((u >> 16) & 1u)) >> 16);
}

// ---------------- Wi2 (512x512 f32) -> W2T bf16 transposed [n][k] ----------------
__global__ __launch_bounds__(256) void wi2t_kernel(const float* __restrict__ Wi2,
                                                   unsigned short* __restrict__ W2T) {
  __shared__ float tile[32][33];
  const int t = threadIdx.x;
  const int bk = blockIdx.x, bn = blockIdx.y;
  const int r = t >> 5, c = t & 31;
#pragma unroll
  for (int p = 0; p < 4; p++) {
    int rr = p * 8 + r;
    tile[rr][c] = Wi2[(bk * 32 + rr) * 512 + bn * 32 + c];
  }
  __syncthreads();
#pragma unroll
  for (int p = 0; p < 4; p++) {
    int rr = p * 8 + r;
    W2T[(bn * 32 + rr) * 512 + bk * 32 + c] = f2bf(tile[c][rr]);
  }
}

// ---------------- U = S @ Wi1[0:128], V = S @ Wi1[128:256]  (2048x128 @ 128x512) ----------------
__global__ __launch_bounds__(256) void uv_kernel(const float* __restrict__ S,
                                                 const float* __restrict__ Wi1,
                                                 float* __restrict__ U, float* __restrict__ V) {
  __shared__ float st[128][12];
  const int t = threadIdx.x;
  const int row0 = blockIdx.x * 8;
  for (int idx = t; idx < 1024; idx += 256) {
    int r = idx >> 7, k = idx & 127;
    st[k][r] = S[(row0 + r) * 128 + k];
  }
  __syncthreads();
  float au0[8], au1[8], av0[8], av1[8];
#pragma unroll
  for (int r = 0; r < 8; r++) { au0[r] = 0.f; au1[r] = 0.f; av0[r] = 0.f; av1[r] = 0.f; }
  for (int k = 0; k < 128; k++) {
    float wt0 = Wi1[k * 512 + t];
    float wt1 = Wi1[k * 512 + 256 + t];
    float wb0 = Wi1[(k + 128) * 512 + t];
    float wb1 = Wi1[(k + 128) * 512 + 256 + t];
    float4 sA = *(const float4*)&st[k][0];
    float4 sB = *(const float4*)&st[k][4];
    float s8[8] = {sA.x, sA.y, sA.z, sA.w, sB.x, sB.y, sB.z, sB.w};
#pragma unroll
    for (int r = 0; r < 8; r++) {
      au0[r] += s8[r] * wt0;
      au1[r] += s8[r] * wt1;
      av0[r] += s8[r] * wb0;
      av1[r] += s8[r] * wb1;
    }
  }
#pragma unroll
  for (int r = 0; r < 8; r++) {
    U[(row0 + r) * 512 + t]       = au0[r];
    U[(row0 + r) * 512 + 256 + t] = au1[r];
    V[(row0 + r) * 512 + t]       = av0[r];
    V[(row0 + r) * 512 + 256 + t] = av1[r];
  }
}

// ---------------- generic M=32 GEMM with k-split partials: P[ks][m][n] = A[32xK] @ W[KxN] ----------------
__global__ __launch_bounds__(512) void gemm32_part(const float* __restrict__ A,
                                                   const float* __restrict__ W,
                                                   float* __restrict__ P,
                                                   int K, int N, int L, int CH, int chsh) {
  __shared__ float At[256][36];
  const int t = threadIdx.x;
  const int nb = blockIdx.x, ks = blockIdx.y;
  const int c0 = nb * 1024 + t;
  const int c1 = c0 + 512;
  const int off1 = (c1 < N) ? 512 : 0;
  const int k0 = ks * L;
  float acc0[32], acc1[32];
#pragma unroll
  for (int m = 0; m < 32; m++) { acc0[m] = 0.f; acc1[m] = 0.f; }
  for (int kc = 0; kc < L; kc += CH) {
    __syncthreads();
    const int tot = CH << 5;
    for (int idx = t; idx < tot; idx += 512) {
      int k = idx & (CH - 1), m = idx >> chsh;
      At[k][m] = A[m * K + k0 + kc + k];
    }
    __syncthreads();
    const float* wp = W + (size_t)(k0 + kc) * N + c0;
    for (int k = 0; k < CH; k++) {
      float w0 = wp[0];
      float w1 = wp[off1];
      wp += N;
      const float4* ar = (const float4*)&At[k][0];
#pragma unroll
      for (int mg = 0; mg < 8; mg++) {
        float4 a4 = ar[mg];
        acc0[mg * 4 + 0] += a4.x * w0; acc0[mg * 4 + 1] += a4.y * w0;
        acc0[mg * 4 + 2] += a4.z * w0; acc0[mg * 4 + 3] += a4.w * w0;
        acc1[mg * 4 + 0] += a4.x * w1; acc1[mg * 4 + 1] += a4.y * w1;
        acc1[mg * 4 + 2] += a4.z * w1; acc1[mg * 4 + 3] += a4.w * w1;
      }
    }
  }
  float* Pr = P + (size_t)ks * 32 * N;
#pragma unroll
  for (int m = 0; m < 32; m++) {
    Pr[m * N + c0] = acc0[m];
    if (off1) Pr[m * N + c1] = acc1[m];
  }
}

// ---------------- reduce partials + bias + activation ----------------
__global__ __launch_bounds__(256) void reduce_kernel(const float* __restrict__ P,
                                                     const float* __restrict__ bias,
                                                     float* __restrict__ dst,
                                                     int lnN, int KS, int act) {
  const int idx = blockIdx.x * 256 + threadIdx.x;
  const int N = 1 << lnN;
  const int m = idx >> lnN, n = idx & (N - 1);
  float s = 0.f;
  for (int p = 0; p < KS; p++) s += P[((size_t)(p * 32 + m) << lnN) + n];
  s += bias[n];
  if (act == 1) s = fmaxf(s, 0.f);
  else if (act == 2) s = tanhf(s);
  dst[idx] = s;
}

// ---------------- interaction core: Hsum[b,i,:] = sum_{j!=i} relu( relu(U[b,i]+V[b,j]+bi1) @ Wi2 + bi2 ) ----------------
__global__ __launch_bounds__(256, 2) void inter_kernel(const float* __restrict__ U,
                                                       const float* __restrict__ V,
                                                       const unsigned short* __restrict__ W2T,
                                                       const float* __restrict__ bi1,
                                                       const float* __restrict__ bi2,
                                                       float* __restrict__ Hsum) {
  __shared__ __align__(16) unsigned short Albuf[16384]; // 128 rows x 128 k bf16, swizzled
  __shared__ __align__(16) unsigned short Btbuf[16384]; // 128 n    x 128 k bf16, swizzled
  __shared__ float ub[2][512];

  const int t = threadIdx.x;
  const int nt = blockIdx.x;   // n-tile 0..3
  const int it = blockIdx.y;   // i-pair 0..31
  const int b  = blockIdx.z;   // batch 0..31
  const int wc_base = nt * 128;

  for (int idx = t; idx < 1024; idx += 256) {
    int ii = idx >> 9, k = idx & 511;
    ub[ii][k] = U[(size_t)(b * 64 + it * 2 + ii) * 512 + k] + bi1[k];
  }

  f32x16 acc[2][2];
#pragma unroll
  for (int mi = 0; mi < 2; mi++)
#pragma unroll
    for (int ni = 0; ni < 2; ni++)
#pragma unroll
      for (int r = 0; r < 16; r++) acc[mi][ni][r] = 0.0f;

  const int w = t >> 6, l = t & 63;
  const int wr = (w >> 1) * 64, wcl = (w & 1) * 64;
  const int lrow = l & 31, lh = l >> 5;
  const int kq = (t & 31) * 4;   // staging: 4 consecutive k per thread
  const int halfj = t >> 5;      // staging: 0..7

  for (int kc = 0; kc < 512; kc += 128) {
    __syncthreads();
    // ---- stage A = h1 chunk (rows = ii*64+j, k local 0..127) ----
#pragma unroll
    for (int jt = 0; jt < 8; jt++) {
      int j = jt * 8 + halfj;
      float4 v4 = *(const float4*)&V[(size_t)(b * 64 + j) * 512 + kc + kq];
#pragma unroll
      for (int ii = 0; ii < 2; ii++) {
        float4 u4 = *(const float4*)&ub[ii][kc + kq];
        int row = ii * 64 + j;
        ushort4 pk;
        pk.x = f2bf(fmaxf(v4.x + u4.x, 0.0f));
        pk.y = f2bf(fmaxf(v4.y + u4.y, 0.0f));
        pk.z = f2bf(fmaxf(v4.z + u4.z, 0.0f));
        pk.w = f2bf(fmaxf(v4.w + u4.w, 0.0f));
        int off = (row * 256 + kq * 2) ^ ((row & 15) << 4);
        *(ushort4*)((char*)Albuf + off) = pk;
      }
    }
    // ---- stage B = W2T chunk ----
#pragma unroll
    for (int itb = 0; itb < 16; itb++) {
      int idx4 = itb * 256 + t;
      int n = idx4 >> 5;
      int k4 = (idx4 & 31) * 4;
      ushort4 u4 = *(const ushort4*)&W2T[(size_t)(wc_base + n) * 512 + kc + k4];
      int off = (n * 256 + k4 * 2) ^ ((n & 15) << 4);
      *(ushort4*)((char*)Btbuf + off) = u4;
    }
    __syncthreads();
    // ---- MFMA: each wave computes 64x64 via 2x2 frags of 32x32x16 ----
#pragma unroll
    for (int ks = 0; ks < 8; ks++) {
      const int kb = ks * 16 + lh * 8;
      bf16x8 afrag[2], bfrag[2];
#pragma unroll
      for (int mi = 0; mi < 2; mi++) {
        int row = wr + mi * 32 + lrow;
        int off = (row * 256 + kb * 2) ^ ((row & 15) << 4);
        afrag[mi] = *(const bf16x8*)((const char*)Albuf + off);
      }
#pragma unroll
      for (int ni = 0; ni < 2; ni++) {
        int n = wcl + ni * 32 + lrow;
        int off = (n * 256 + kb * 2) ^ ((n & 15) << 4);
        bfrag[ni] = *(const bf16x8*)((const char*)Btbuf + off);
      }
#pragma unroll
      for (int mi = 0; mi < 2; mi++)
#pragma unroll
        for (int ni = 0; ni < 2; ni++)
          acc[mi][ni] = __builtin_amdgcn_mfma_f32_32x32x16_bf16(afrag[mi], bfrag[ni], acc[mi][ni], 0, 0, 0);
    }
  }

  // ---- epilogue: relu(+bi2), sum over j excluding j==i, write Hsum ----
  const int ii = wr >> 6;
  const int iglob = it * 2 + ii;
  const int mi_d = iglob >> 5;
  const int r5 = iglob & 31;
  const int half_d = (r5 >> 2) & 1;
  const int reg_d = (r5 & 3) + 4 * (r5 >> 3);
#pragma unroll
  for (int ni = 0; ni < 2; ni++) {
    int c = wc_base + wcl + ni * 32 + lrow;
    float b2 = bi2[c];
    float s = 0.0f;
#pragma unroll
    for (int mi = 0; mi < 2; mi++)
#pragma unroll
      for (int r = 0; r < 16; r++) {
        float v = fmaxf(acc[mi][ni][r] + b2, 0.0f);
        bool isdiag = (mi == mi_d) && (r == reg_d) && (lh == half_d);
        s += isdiag ? 0.0f : v;
      }
    s += __shfl_xor(s, 32);
    if (lh == 0) Hsum[(size_t)(b * 64 + iglob) * 512 + c] = s;
  }
}

// ---------------- interactions = (Hsum/63) @ Wi3 + bi3   (2048x512 @ 512x128) ----------------
__global__ __launch_bounds__(256) void k3_kernel(const float* __restrict__ Hsum,
                                                 const float* __restrict__ Wi3,
                                                 const float* __restrict__ bi3,
                                                 float* __restrict__ inter) {
  __shared__ float st[512][20];
  const int t = threadIdx.x;
  const int row0 = blockIdx.x * 16;
  for (int idx = t; idx < 8192; idx += 256) {
    int r = idx >> 9, k = idx & 511;
    st[k][r] = Hsum[(row0 + r) * 512 + k] * (1.0f / 63.0f);
  }
  __syncthreads();
  const int c = t & 63;
  const int rg = t >> 6;
  float a0[4] = {0.f, 0.f, 0.f, 0.f}, a1[4] = {0.f, 0.f, 0.f, 0.f};
  for (int k = 0; k < 512; k++) {
    float w0 = Wi3[k * 128 + c];
    float w1 = Wi3[k * 128 + 64 + c];
    float4 h = *(const float4*)&st[k][rg * 4];
    a0[0] += h.x * w0; a0[1] += h.y * w0; a0[2] += h.z * w0; a0[3] += h.w * w0;
    a1[0] += h.x * w1; a1[1] += h.y * w1; a1[2] += h.z * w1; a1[3] += h.w * w1;
  }
  float b0 = bi3[c], b1 = bi3[64 + c];
#pragma unroll
  for (int r = 0; r < 4; r++) {
    inter[(row0 + rg * 4 + r) * 128 + c]      = a0[r] + b0;
    inter[(row0 + rg * 4 + r) * 128 + 64 + c] = a1[r] + b1;
  }
}

// ---------------- final combine ----------------
__global__ __launch_bounds__(256) void combine_kernel(const float* __restrict__ S,
                                                      const float* __restrict__ inter,
                                                      const float* __restrict__ coord,
                                                      float* __restrict__ out0) {
  const int i = blockIdx.x * 256 + threadIdx.x;
  float4 s = ((const float4*)S)[i];
  float4 a = ((const float4*)inter)[i];
  float4 c = ((const float4*)coord)[i];
  float4 o;
  o.x = s.x + 0.1f * (a.x + c.x);
  o.y = s.y + 0.1f * (a.y + c.y);
  o.z = s.z + 0.1f * (a.z + c.z);
  o.w = s.w + 0.1f * (a.w + c.w);
  ((float4*)out0)[i] = o;
}

extern "C" void kernel_launch(void* const* d_in, const int* in_sizes, int n_in,
                              void* d_out, int out_size, void* d_ws, size_t ws_size,
                              hipStream_t stream) {
  const float* states = (const float*)d_in[0];
  const float* Wq  = (const float*)d_in[2];
  const float* bq  = (const float*)d_in[3];
  const float* Wi1 = (const float*)d_in[4];
  const float* bi1 = (const float*)d_in[5];
  const float* Wi2 = (const float*)d_in[6];
  const float* bi2 = (const float*)d_in[7];
  const float* Wi3 = (const float*)d_in[8];
  const float* bi3 = (const float*)d_in[9];
  const float* Wc1 = (const float*)d_in[10];
  const float* bc1 = (const float*)d_in[11];
  const float* Wc2 = (const float*)d_in[12];
  const float* bc2 = (const float*)d_in[13];
  const float* Wc3 = (const float*)d_in[14];
  const float* bc3 = (const float*)d_in[15];

  float* out   = (float*)d_out;
  float* out0  = out;            // coordinated_states (B,A,D)
  float* qf    = out + 262144;   // quantum_features (B,F)
  float* inter = out + 524288;   // interactions (B,A,D)
  float* coord = out + 786432;   // coordination (B,A,D)

  char* ws = (char*)d_ws;
  float*          P    = (float*)(ws);                                  // 32MB partials
  float*          U    = (float*)(ws + ((size_t)32 << 20));             // 4MB
  float*          V    = (float*)(ws + ((size_t)36 << 20));             // 4MB
  unsigned short* W2T  = (unsigned short*)(ws + ((size_t)40 << 20));    // 0.5MB
  float*          Hsum = (float*)(ws + ((size_t)41 << 20));             // 4MB
  float*          c1   = (float*)(ws + ((size_t)45 << 20));             // 64KB
  float*          c2   = (float*)(ws + ((size_t)45 << 20) + 65536);     // 64KB

  // prep
  wi2t_kernel<<<dim3(16, 16), 256, 0, stream>>>(Wi2, W2T);
  uv_kernel<<<256, 256, 0, stream>>>(states, Wi1, U, V);

  // quantum features: qf = tanh(states @ Wq + bq)
  gemm32_part<<<dim3(8, 32), 512, 0, stream>>>(states, Wq, P, 8192, 8192, 256, 256, 8);
  reduce_kernel<<<1024, 256, 0, stream>>>(P, bq, qf, 13, 32, 2);

  // interactions
  inter_kernel<<<dim3(4, 32, 32), 256, 0, stream>>>(U, V, W2T, bi1, bi2, Hsum);
  k3_kernel<<<128, 256, 0, stream>>>(Hsum, Wi3, bi3, inter);

  // coordination chain
  gemm32_part<<<dim3(1, 128), 512, 0, stream>>>(qf, Wc1, P, 8192, 512, 64, 64, 6);
  reduce_kernel<<<64, 256, 0, stream>>>(P, bc1, c1, 9, 128, 1);
  gemm32_part<<<dim3(1, 32), 512, 0, stream>>>(c1, Wc2, P, 512, 512, 16, 16, 4);
  reduce_kernel<<<64, 256, 0, stream>>>(P, bc2, c2, 9, 32, 1);
  gemm32_part<<<dim3(8, 32), 512, 0, stream>>>(c2, Wc3, P, 512, 8192, 16, 16, 4);
  reduce_kernel<<<1024, 256, 0, stream>>>(P, bc3, coord, 13, 32, 0);

  // final
  combine_kernel<<<256, 256, 0, stream>>>(states, inter, coord, out0);
}

// Round 2
// 519.777 us; speedup vs baseline: 1.0102x; 1.0102x over previous
//
#include <hip/hip_runtime.h>

typedef __attribute__((ext_vector_type(8))) short bf16x8;
typedef __attribute__((ext_vector_type(16))) float f32x16;

static __device__ __forceinline__ unsigned short f2bf(float x) {
  unsigned int u = __float_as_uint(x);
  return (unsigned short)((u + 0x7FFFu + ((u >> 16) & 1u)) >> 16);
}

// ---------------- Wi2 (512x512 f32) -> W2T bf16 transposed [n][k] ----------------
__global__ __launch_bounds__(256) void wi2t_kernel(const float* __restrict__ Wi2,
                                                   unsigned short* __restrict__ W2T) {
  __shared__ float tile[32][33];
  const int t = threadIdx.x;
  const int bk = blockIdx.x, bn = blockIdx.y;
  const int r = t >> 5, c = t & 31;
#pragma unroll
  for (int p = 0; p < 4; p++) {
    int rr = p * 8 + r;
    tile[rr][c] = Wi2[(bk * 32 + rr) * 512 + bn * 32 + c];
  }
  __syncthreads();
#pragma unroll
  for (int p = 0; p < 4; p++) {
    int rr = p * 8 + r;
    W2T[(bn * 32 + rr) * 512 + bk * 32 + c] = f2bf(tile[c][rr]);
  }
}

// ---------------- U = S @ Wi1[0:128], V = S @ Wi1[128:256]  (2048x128 @ 128x512) ----------------
__global__ __launch_bounds__(256) void uv_kernel(const float* __restrict__ S,
                                                 const float* __restrict__ Wi1,
                                                 float* __restrict__ U, float* __restrict__ V) {
  __shared__ float st[128][12];
  const int t = threadIdx.x;
  const int row0 = blockIdx.x * 8;
  for (int idx = t; idx < 1024; idx += 256) {
    int r = idx >> 7, k = idx & 127;
    st[k][r] = S[(row0 + r) * 128 + k];
  }
  __syncthreads();
  float au0[8], au1[8], av0[8], av1[8];
#pragma unroll
  for (int r = 0; r < 8; r++) { au0[r] = 0.f; au1[r] = 0.f; av0[r] = 0.f; av1[r] = 0.f; }
  for (int k = 0; k < 128; k++) {
    float wt0 = Wi1[k * 512 + t];
    float wt1 = Wi1[k * 512 + 256 + t];
    float wb0 = Wi1[(k + 128) * 512 + t];
    float wb1 = Wi1[(k + 128) * 512 + 256 + t];
    float4 sA = *(const float4*)&st[k][0];
    float4 sB = *(const float4*)&st[k][4];
    float s8[8] = {sA.x, sA.y, sA.z, sA.w, sB.x, sB.y, sB.z, sB.w};
#pragma unroll
    for (int r = 0; r < 8; r++) {
      au0[r] += s8[r] * wt0;
      au1[r] += s8[r] * wt1;
      av0[r] += s8[r] * wb0;
      av1[r] += s8[r] * wb1;
    }
  }
#pragma unroll
  for (int r = 0; r < 8; r++) {
    U[(row0 + r) * 512 + t]       = au0[r];
    U[(row0 + r) * 512 + 256 + t] = au1[r];
    V[(row0 + r) * 512 + t]       = av0[r];
    V[(row0 + r) * 512 + 256 + t] = av1[r];
  }
}

// ---------------- M=32 GEMM, k-split partials: P[ks][m][n] = A[32xK] @ W[KxN] ----------------
// grid (N/256, KS); block 256. Thread: 8 rows x 4 cols. Requires L % 64 == 0, N % 256 == 0.
__global__ __launch_bounds__(256, 4) void gemm32b(const float* __restrict__ A,
                                                  const float* __restrict__ W,
                                                  float* __restrict__ P,
                                                  int K, int N, int L) {
  __shared__ float At[64][36];
  const int t = threadIdx.x;
  const int nb = blockIdx.x, ks = blockIdx.y;
  const int k0 = ks * L;
  const int rg = t >> 6;                 // wave-uniform row group
  const int c = nb * 256 + (t & 63) * 4;
  float acc[8][4];
#pragma unroll
  for (int m = 0; m < 8; m++)
#pragma unroll
    for (int n = 0; n < 4; n++) acc[m][n] = 0.f;

  for (int kc = 0; kc < L; kc += 64) {
    __syncthreads();
#pragma unroll
    for (int i = 0; i < 8; i++) {
      int idx = i * 256 + t;
      int k = idx & 63, m = idx >> 6;
      At[k][m] = A[m * K + k0 + kc + k];
    }
    __syncthreads();
    const float* wp = W + (size_t)(k0 + kc) * N + c;
#pragma unroll 4
    for (int k = 0; k < 64; k++) {
      float4 w4 = *(const float4*)wp;
      wp += N;
      const float4* ar = (const float4*)&At[k][rg * 8];
      float4 a0 = ar[0], a1 = ar[1];
      float a8[8] = {a0.x, a0.y, a0.z, a0.w, a1.x, a1.y, a1.z, a1.w};
#pragma unroll
      for (int m = 0; m < 8; m++) {
        acc[m][0] += a8[m] * w4.x;
        acc[m][1] += a8[m] * w4.y;
        acc[m][2] += a8[m] * w4.z;
        acc[m][3] += a8[m] * w4.w;
      }
    }
  }
  float* Pr = P + (size_t)ks * 32 * N + (size_t)(rg * 8) * N + c;
#pragma unroll
  for (int m = 0; m < 8; m++) {
    float4 o; o.x = acc[m][0]; o.y = acc[m][1]; o.z = acc[m][2]; o.w = acc[m][3];
    *(float4*)&Pr[(size_t)m * N] = o;
  }
}

// ---------------- reduce partials + bias + activation ----------------
__global__ __launch_bounds__(256) void reduce_kernel(const float* __restrict__ P,
                                                     const float* __restrict__ bias,
                                                     float* __restrict__ dst,
                                                     int lnN, int KS, int act) {
  const int idx = blockIdx.x * 256 + threadIdx.x;
  const int N = 1 << lnN;
  const int m = idx >> lnN, n = idx & (N - 1);
  float s = 0.f;
  for (int p = 0; p < KS; p++) s += P[((size_t)(p * 32 + m) << lnN) + n];
  s += bias[n];
  if (act == 1) s = fmaxf(s, 0.f);
  else if (act == 2) s = tanhf(s);
  dst[idx] = s;
}

// ---------------- interaction core: Hsum[b,i,:] = sum_{j!=i} relu( relu(U[b,i]+V[b,j]+bi1) @ Wi2 + bi2 ) ----------------
__global__ __launch_bounds__(256, 2) void inter_kernel(const float* __restrict__ U,
                                                       const float* __restrict__ V,
                                                       const unsigned short* __restrict__ W2T,
                                                       const float* __restrict__ bi1,
                                                       const float* __restrict__ bi2,
                                                       float* __restrict__ Hsum) {
  __shared__ __align__(16) unsigned short Albuf[16384]; // 128 rows x 128 k bf16, swizzled
  __shared__ __align__(16) unsigned short Btbuf[16384]; // 128 n    x 128 k bf16, swizzled
  __shared__ float ub[2][512];

  const int t = threadIdx.x;
  const int nt = blockIdx.x;   // n-tile 0..3
  const int it = blockIdx.y;   // i-pair 0..31
  const int b  = blockIdx.z;   // batch 0..31
  const int wc_base = nt * 128;

  for (int idx = t; idx < 1024; idx += 256) {
    int ii = idx >> 9, k = idx & 511;
    ub[ii][k] = U[(size_t)(b * 64 + it * 2 + ii) * 512 + k] + bi1[k];
  }

  f32x16 acc[2][2];
#pragma unroll
  for (int mi = 0; mi < 2; mi++)
#pragma unroll
    for (int ni = 0; ni < 2; ni++)
#pragma unroll
      for (int r = 0; r < 16; r++) acc[mi][ni][r] = 0.0f;

  const int w = t >> 6, l = t & 63;
  const int wr = (w >> 1) * 64, wcl = (w & 1) * 64;
  const int lrow = l & 31, lh = l >> 5;
  const int kq = (t & 31) * 4;   // staging: 4 consecutive k per thread
  const int halfj = t >> 5;      // staging: 0..7

  for (int kc = 0; kc < 512; kc += 128) {
    __syncthreads();
    // ---- stage A = h1 chunk (rows = ii*64+j, k local 0..127) ----
#pragma unroll
    for (int jt = 0; jt < 8; jt++) {
      int j = jt * 8 + halfj;
      float4 v4 = *(const float4*)&V[(size_t)(b * 64 + j) * 512 + kc + kq];
#pragma unroll
      for (int ii = 0; ii < 2; ii++) {
        float4 u4 = *(const float4*)&ub[ii][kc + kq];
        int row = ii * 64 + j;
        ushort4 pk;
        pk.x = f2bf(fmaxf(v4.x + u4.x, 0.0f));
        pk.y = f2bf(fmaxf(v4.y + u4.y, 0.0f));
        pk.z = f2bf(fmaxf(v4.z + u4.z, 0.0f));
        pk.w = f2bf(fmaxf(v4.w + u4.w, 0.0f));
        int off = (row * 256 + kq * 2) ^ ((row & 15) << 4);
        *(ushort4*)((char*)Albuf + off) = pk;
      }
    }
    // ---- stage B = W2T chunk ----
#pragma unroll
    for (int itb = 0; itb < 16; itb++) {
      int idx4 = itb * 256 + t;
      int n = idx4 >> 5;
      int k4 = (idx4 & 31) * 4;
      ushort4 u4 = *(const ushort4*)&W2T[(size_t)(wc_base + n) * 512 + kc + k4];
      int off = (n * 256 + k4 * 2) ^ ((n & 15) << 4);
      *(ushort4*)((char*)Btbuf + off) = u4;
    }
    __syncthreads();
    // ---- MFMA: each wave computes 64x64 via 2x2 frags of 32x32x16 ----
#pragma unroll
    for (int ks = 0; ks < 8; ks++) {
      const int kb = ks * 16 + lh * 8;
      bf16x8 afrag[2], bfrag[2];
#pragma unroll
      for (int mi = 0; mi < 2; mi++) {
        int row = wr + mi * 32 + lrow;
        int off = (row * 256 + kb * 2) ^ ((row & 15) << 4);
        afrag[mi] = *(const bf16x8*)((const char*)Albuf + off);
      }
#pragma unroll
      for (int ni = 0; ni < 2; ni++) {
        int n = wcl + ni * 32 + lrow;
        int off = (n * 256 + kb * 2) ^ ((n & 15) << 4);
        bfrag[ni] = *(const bf16x8*)((const char*)Btbuf + off);
      }
#pragma unroll
      for (int mi = 0; mi < 2; mi++)
#pragma unroll
        for (int ni = 0; ni < 2; ni++)
          acc[mi][ni] = __builtin_amdgcn_mfma_f32_32x32x16_bf16(afrag[mi], bfrag[ni], acc[mi][ni], 0, 0, 0);
    }
  }

  // ---- epilogue: relu(+bi2), sum over j excluding j==i, write Hsum ----
  const int ii = wr >> 6;
  const int iglob = it * 2 + ii;
  const int mi_d = iglob >> 5;
  const int r5 = iglob & 31;
  const int half_d = (r5 >> 2) & 1;
  const int reg_d = (r5 & 3) + 4 * (r5 >> 3);
#pragma unroll
  for (int ni = 0; ni < 2; ni++) {
    int c = wc_base + wcl + ni * 32 + lrow;
    float b2 = bi2[c];
    float s = 0.0f;
#pragma unroll
    for (int mi = 0; mi < 2; mi++)
#pragma unroll
      for (int r = 0; r < 16; r++) {
        float v = fmaxf(acc[mi][ni][r] + b2, 0.0f);
        bool isdiag = (mi == mi_d) && (r == reg_d) && (lh == half_d);
        s += isdiag ? 0.0f : v;
      }
    s += __shfl_xor(s, 32);
    if (lh == 0) Hsum[(size_t)(b * 64 + iglob) * 512 + c] = s;
  }
}

// ---------------- interactions = (Hsum/63) @ Wi3 + bi3   (2048x512 @ 512x128) ----------------
__global__ __launch_bounds__(256) void k3_kernel(const float* __restrict__ Hsum,
                                                 const float* __restrict__ Wi3,
                                                 const float* __restrict__ bi3,
                                                 float* __restrict__ inter) {
  __shared__ float st[512][20];
  const int t = threadIdx.x;
  const int row0 = blockIdx.x * 16;
  for (int idx = t; idx < 8192; idx += 256) {
    int r = idx >> 9, k = idx & 511;
    st[k][r] = Hsum[(row0 + r) * 512 + k] * (1.0f / 63.0f);
  }
  __syncthreads();
  const int c = t & 63;
  const int rg = t >> 6;
  float a0[4] = {0.f, 0.f, 0.f, 0.f}, a1[4] = {0.f, 0.f, 0.f, 0.f};
  for (int k = 0; k < 512; k++) {
    float w0 = Wi3[k * 128 + c];
    float w1 = Wi3[k * 128 + 64 + c];
    float4 h = *(const float4*)&st[k][rg * 4];
    a0[0] += h.x * w0; a0[1] += h.y * w0; a0[2] += h.z * w0; a0[3] += h.w * w0;
    a1[0] += h.x * w1; a1[1] += h.y * w1; a1[2] += h.z * w1; a1[3] += h.w * w1;
  }
  float b0 = bi3[c], b1 = bi3[64 + c];
#pragma unroll
  for (int r = 0; r < 4; r++) {
    inter[(row0 + rg * 4 + r) * 128 + c]      = a0[r] + b0;
    inter[(row0 + rg * 4 + r) * 128 + 64 + c] = a1[r] + b1;
  }
}

// ---------------- final combine ----------------
__global__ __launch_bounds__(256) void combine_kernel(const float* __restrict__ S,
                                                      const float* __restrict__ inter,
                                                      const float* __restrict__ coord,
                                                      float* __restrict__ out0) {
  const int i = blockIdx.x * 256 + threadIdx.x;
  float4 s = ((const float4*)S)[i];
  float4 a = ((const float4*)inter)[i];
  float4 c = ((const float4*)coord)[i];
  float4 o;
  o.x = s.x + 0.1f * (a.x + c.x);
  o.y = s.y + 0.1f * (a.y + c.y);
  o.z = s.z + 0.1f * (a.z + c.z);
  o.w = s.w + 0.1f * (a.w + c.w);
  ((float4*)out0)[i] = o;
}

extern "C" void kernel_launch(void* const* d_in, const int* in_sizes, int n_in,
                              void* d_out, int out_size, void* d_ws, size_t ws_size,
                              hipStream_t stream) {
  const float* states = (const float*)d_in[0];
  const float* Wq  = (const float*)d_in[2];
  const float* bq  = (const float*)d_in[3];
  const float* Wi1 = (const float*)d_in[4];
  const float* bi1 = (const float*)d_in[5];
  const float* Wi2 = (const float*)d_in[6];
  const float* bi2 = (const float*)d_in[7];
  const float* Wi3 = (const float*)d_in[8];
  const float* bi3 = (const float*)d_in[9];
  const float* Wc1 = (const float*)d_in[10];
  const float* bc1 = (const float*)d_in[11];
  const float* Wc2 = (const float*)d_in[12];
  const float* bc2 = (const float*)d_in[13];
  const float* Wc3 = (const float*)d_in[14];
  const float* bc3 = (const float*)d_in[15];

  float* out   = (float*)d_out;
  float* out0  = out;            // coordinated_states (B,A,D)
  float* qf    = out + 262144;   // quantum_features (B,F)
  float* inter = out + 524288;   // interactions (B,A,D)
  float* coord = out + 786432;   // coordination (B,A,D)

  char* ws = (char*)d_ws;
  float*          P    = (float*)(ws);                                  // 32MB partials
  float*          U    = (float*)(ws + ((size_t)32 << 20));             // 4MB
  float*          V    = (float*)(ws + ((size_t)36 << 20));             // 4MB
  unsigned short* W2T  = (unsigned short*)(ws + ((size_t)40 << 20));    // 0.5MB
  float*          Hsum = (float*)(ws + ((size_t)41 << 20));             // 4MB
  float*          c1   = (float*)(ws + ((size_t)45 << 20));             // 64KB
  float*          c2   = (float*)(ws + ((size_t)45 << 20) + 65536);     // 64KB

  // prep
  wi2t_kernel<<<dim3(16, 16), 256, 0, stream>>>(Wi2, W2T);
  uv_kernel<<<256, 256, 0, stream>>>(states, Wi1, U, V);

  // quantum features: qf = tanh(states @ Wq + bq)   K=8192 N=8192, KS=32, L=256
  gemm32b<<<dim3(32, 32), 256, 0, stream>>>(states, Wq, P, 8192, 8192, 256);
  reduce_kernel<<<1024, 256, 0, stream>>>(P, bq, qf, 13, 32, 2);

  // interactions
  inter_kernel<<<dim3(4, 32, 32), 256, 0, stream>>>(U, V, W2T, bi1, bi2, Hsum);
  k3_kernel<<<128, 256, 0, stream>>>(Hsum, Wi3, bi3, inter);

  // coordination chain
  // c1 = relu(qf @ Wc1 + bc1): K=8192, N=512, KS=64, L=128
  gemm32b<<<dim3(2, 64), 256, 0, stream>>>(qf, Wc1, P, 8192, 512, 128);
  reduce_kernel<<<64, 256, 0, stream>>>(P, bc1, c1, 9, 64, 1);
  // c2 = relu(c1 @ Wc2 + bc2): K=512, N=512, KS=8, L=64
  gemm32b<<<dim3(2, 8), 256, 0, stream>>>(c1, Wc2, P, 512, 512, 64);
  reduce_kernel<<<64, 256, 0, stream>>>(P, bc2, c2, 9, 8, 1);
  // coord = c2 @ Wc3 + bc3: K=512, N=8192, KS=8, L=64
  gemm32b<<<dim3(32, 8), 256, 0, stream>>>(c2, Wc3, P, 512, 8192, 64);
  reduce_kernel<<<1024, 256, 0, stream>>>(P, bc3, coord, 13, 8, 0);

  // final
  combine_kernel<<<256, 256, 0, stream>>>(states, inter, coord, out0);
}

// Round 3
// 458.778 us; speedup vs baseline: 1.1445x; 1.1330x over previous
//
#include <hip/hip_runtime.h>

typedef __attribute__((ext_vector_type(8))) short bf16x8;
typedef __attribute__((ext_vector_type(16))) float f32x16;

static __device__ __forceinline__ unsigned short f2bf(float x) {
  unsigned int u = __float_as_uint(x);
  return (unsigned short)((u + 0x7FFFu + ((u >> 16) & 1u)) >> 16);
}

// ---------------- Wi2 (512x512 f32) -> W2T bf16 transposed [n][k] ----------------
__global__ __launch_bounds__(256) void wi2t_kernel(const float* __restrict__ Wi2,
                                                   unsigned short* __restrict__ W2T) {
  __shared__ float tile[32][33];
  const int t = threadIdx.x;
  const int bk = blockIdx.x, bn = blockIdx.y;
  const int r = t >> 5, c = t & 31;
#pragma unroll
  for (int p = 0; p < 4; p++) {
    int rr = p * 8 + r;
    tile[rr][c] = Wi2[(bk * 32 + rr) * 512 + bn * 32 + c];
  }
  __syncthreads();
#pragma unroll
  for (int p = 0; p < 4; p++) {
    int rr = p * 8 + r;
    W2T[(bn * 32 + rr) * 512 + bk * 32 + c] = f2bf(tile[c][rr]);
  }
}

// ---------------- U = S @ Wi1[0:128], V = S @ Wi1[128:256]  (2048x128 @ 128x512) ----------------
__global__ __launch_bounds__(256) void uv_kernel(const float* __restrict__ S,
                                                 const float* __restrict__ Wi1,
                                                 float* __restrict__ U, float* __restrict__ V) {
  __shared__ float st[128][12];
  const int t = threadIdx.x;
  const int row0 = blockIdx.x * 8;
  for (int idx = t; idx < 1024; idx += 256) {
    int r = idx >> 7, k = idx & 127;
    st[k][r] = S[(row0 + r) * 128 + k];
  }
  __syncthreads();
  float au0[8], au1[8], av0[8], av1[8];
#pragma unroll
  for (int r = 0; r < 8; r++) { au0[r] = 0.f; au1[r] = 0.f; av0[r] = 0.f; av1[r] = 0.f; }
#pragma unroll 4
  for (int k = 0; k < 128; k++) {
    float wt0 = Wi1[k * 512 + t];
    float wt1 = Wi1[k * 512 + 256 + t];
    float wb0 = Wi1[(k + 128) * 512 + t];
    float wb1 = Wi1[(k + 128) * 512 + 256 + t];
    float4 sA = *(const float4*)&st[k][0];
    float4 sB = *(const float4*)&st[k][4];
    float s8[8] = {sA.x, sA.y, sA.z, sA.w, sB.x, sB.y, sB.z, sB.w};
#pragma unroll
    for (int r = 0; r < 8; r++) {
      au0[r] += s8[r] * wt0;
      au1[r] += s8[r] * wt1;
      av0[r] += s8[r] * wb0;
      av1[r] += s8[r] * wb1;
    }
  }
#pragma unroll
  for (int r = 0; r < 8; r++) {
    U[(row0 + r) * 512 + t]       = au0[r];
    U[(row0 + r) * 512 + 256 + t] = au1[r];
    V[(row0 + r) * 512 + t]       = av0[r];
    V[(row0 + r) * 512 + 256 + t] = av1[r];
  }
}

// ---------------- M=32 GEMM with explicit 2-bank (8-deep) W prefetch ----------------
__device__ __forceinline__ void comp4(const float (*At)[36], int kk, int rg,
                                      const float4 w[4], float acc[8][4]) {
#pragma unroll
  for (int i = 0; i < 4; i++) {
    float4 a0 = *(const float4*)&At[kk + i][rg * 8];
    float4 a1 = *(const float4*)&At[kk + i][rg * 8 + 4];
    float a8[8] = {a0.x, a0.y, a0.z, a0.w, a1.x, a1.y, a1.z, a1.w};
#pragma unroll
    for (int m = 0; m < 8; m++) {
      acc[m][0] += a8[m] * w[i].x;
      acc[m][1] += a8[m] * w[i].y;
      acc[m][2] += a8[m] * w[i].z;
      acc[m][3] += a8[m] * w[i].w;
    }
  }
}

__device__ __forceinline__ void refill4(const float* __restrict__ Wc, int N, int row, float4 w[4]) {
  const float* p = Wc + (size_t)row * N;
#pragma unroll
  for (int j = 0; j < 4; j++) w[j] = *(const float4*)(p + (size_t)j * N);
}

// grid (N/256, KS); block 256. Thread: 8 rows x 4 cols. L % 64 == 0, N % 4 == 0.
__global__ __launch_bounds__(256, 4) void gemm32c(const float* __restrict__ A,
                                                  const float* __restrict__ W,
                                                  float* __restrict__ P,
                                                  int K, int N, int L) {
  __shared__ float At[64][36];
  const int t = threadIdx.x;
  const int nb = blockIdx.x, ks = blockIdx.y;
  const int k0 = ks * L;
  const int rg = t >> 6;                 // wave-uniform row group
  const int c = nb * 256 + (t & 63) * 4;
  float acc[8][4];
#pragma unroll
  for (int m = 0; m < 8; m++) { acc[m][0] = 0.f; acc[m][1] = 0.f; acc[m][2] = 0.f; acc[m][3] = 0.f; }

  const float* Wc = W + c;
  float4 wa[4], wb[4];
  refill4(Wc, N, k0, wa);        // rows k0..k0+3
  refill4(Wc, N, k0 + 4, wb);    // rows k0+4..k0+7

  for (int kc = 0; kc < L; kc += 64) {
    __syncthreads();
#pragma unroll
    for (int i = 0; i < 8; i++) {
      int idx = i * 256 + t;
      int k = idx & 63, m = idx >> 6;
      At[k][m] = A[m * K + k0 + kc + k];
    }
    __syncthreads();
#pragma unroll
    for (int kg = 0; kg < 64; kg += 8) {
      comp4(At, kg, rg, wa, acc);
      refill4(Wc, N, min(k0 + kc + kg + 8, K - 4), wa);
      comp4(At, kg + 4, rg, wb, acc);
      refill4(Wc, N, min(k0 + kc + kg + 12, K - 4), wb);
    }
  }
  float* Pr = P + (size_t)ks * 32 * N + (size_t)(rg * 8) * N + c;
#pragma unroll
  for (int m = 0; m < 8; m++) {
    float4 o; o.x = acc[m][0]; o.y = acc[m][1]; o.z = acc[m][2]; o.w = acc[m][3];
    *(float4*)&Pr[(size_t)m * N] = o;
  }
}

// ---------------- reduce partials + bias + activation ----------------
__global__ __launch_bounds__(256) void reduce_kernel(const float* __restrict__ P,
                                                     const float* __restrict__ bias,
                                                     float* __restrict__ dst,
                                                     int lnN, int KS, int act) {
  const int idx = blockIdx.x * 256 + threadIdx.x;
  const int N = 1 << lnN;
  const int m = idx >> lnN, n = idx & (N - 1);
  float s = 0.f;
#pragma unroll 8
  for (int p = 0; p < KS; p++) s += P[((size_t)(p * 32 + m) << lnN) + n];
  s += bias[n];
  if (act == 1) s = fmaxf(s, 0.f);
  else if (act == 2) s = tanhf(s);
  dst[idx] = s;
}

// ---------------- interaction core: Hsum[b,i,:] = sum_{j!=i} relu( relu(U[b,i]+V[b,j]+bi1) @ Wi2 + bi2 ) ----------------
__global__ __launch_bounds__(256, 2) void inter_kernel(const float* __restrict__ U,
                                                       const float* __restrict__ V,
                                                       const unsigned short* __restrict__ W2T,
                                                       const float* __restrict__ bi1,
                                                       const float* __restrict__ bi2,
                                                       float* __restrict__ Hsum) {
  __shared__ __align__(16) unsigned short Albuf[16384]; // 128 rows x 128 k bf16, swizzled
  __shared__ __align__(16) unsigned short Btbuf[16384]; // 128 n    x 128 k bf16, swizzled
  __shared__ float ub[2][512];

  const int t = threadIdx.x;
  const int nt = blockIdx.x;   // n-tile 0..3
  const int it = blockIdx.y;   // i-pair 0..31
  const int b  = blockIdx.z;   // batch 0..31
  const int wc_base = nt * 128;

  for (int idx = t; idx < 1024; idx += 256) {
    int ii = idx >> 9, k = idx & 511;
    ub[ii][k] = U[(size_t)(b * 64 + it * 2 + ii) * 512 + k] + bi1[k];
  }

  f32x16 acc[2][2];
#pragma unroll
  for (int mi = 0; mi < 2; mi++)
#pragma unroll
    for (int ni = 0; ni < 2; ni++)
#pragma unroll
      for (int r = 0; r < 16; r++) acc[mi][ni][r] = 0.0f;

  const int w = t >> 6, l = t & 63;
  const int wr = (w >> 1) * 64, wcl = (w & 1) * 64;
  const int lrow = l & 31, lh = l >> 5;
  const int kq = (t & 31) * 4;   // staging: 4 consecutive k per thread
  const int halfj = t >> 5;      // staging: 0..7

  for (int kc = 0; kc < 512; kc += 128) {
    __syncthreads();
    // ---- stage A = h1 chunk (rows = ii*64+j, k local 0..127) ----
#pragma unroll
    for (int jt = 0; jt < 8; jt++) {
      int j = jt * 8 + halfj;
      float4 v4 = *(const float4*)&V[(size_t)(b * 64 + j) * 512 + kc + kq];
#pragma unroll
      for (int ii = 0; ii < 2; ii++) {
        float4 u4 = *(const float4*)&ub[ii][kc + kq];
        int row = ii * 64 + j;
        ushort4 pk;
        pk.x = f2bf(fmaxf(v4.x + u4.x, 0.0f));
        pk.y = f2bf(fmaxf(v4.y + u4.y, 0.0f));
        pk.z = f2bf(fmaxf(v4.z + u4.z, 0.0f));
        pk.w = f2bf(fmaxf(v4.w + u4.w, 0.0f));
        int off = (row * 256 + kq * 2) ^ ((row & 15) << 4);
        *(ushort4*)((char*)Albuf + off) = pk;
      }
    }
    // ---- stage B = W2T chunk ----
#pragma unroll
    for (int itb = 0; itb < 16; itb++) {
      int idx4 = itb * 256 + t;
      int n = idx4 >> 5;
      int k4 = (idx4 & 31) * 4;
      ushort4 u4 = *(const ushort4*)&W2T[(size_t)(wc_base + n) * 512 + kc + k4];
      int off = (n * 256 + k4 * 2) ^ ((n & 15) << 4);
      *(ushort4*)((char*)Btbuf + off) = u4;
    }
    __syncthreads();
    // ---- MFMA: each wave computes 64x64 via 2x2 frags of 32x32x16 ----
#pragma unroll
    for (int ks = 0; ks < 8; ks++) {
      const int kb = ks * 16 + lh * 8;
      bf16x8 afrag[2], bfrag[2];
#pragma unroll
      for (int mi = 0; mi < 2; mi++) {
        int row = wr + mi * 32 + lrow;
        int off = (row * 256 + kb * 2) ^ ((row & 15) << 4);
        afrag[mi] = *(const bf16x8*)((const char*)Albuf + off);
      }
#pragma unroll
      for (int ni = 0; ni < 2; ni++) {
        int n = wcl + ni * 32 + lrow;
        int off = (n * 256 + kb * 2) ^ ((n & 15) << 4);
        bfrag[ni] = *(const bf16x8*)((const char*)Btbuf + off);
      }
#pragma unroll
      for (int mi = 0; mi < 2; mi++)
#pragma unroll
        for (int ni = 0; ni < 2; ni++)
          acc[mi][ni] = __builtin_amdgcn_mfma_f32_32x32x16_bf16(afrag[mi], bfrag[ni], acc[mi][ni], 0, 0, 0);
    }
  }

  // ---- epilogue: relu(+bi2), sum over j excluding j==i, write Hsum ----
  const int ii = wr >> 6;
  const int iglob = it * 2 + ii;
  const int mi_d = iglob >> 5;
  const int r5 = iglob & 31;
  const int half_d = (r5 >> 2) & 1;
  const int reg_d = (r5 & 3) + 4 * (r5 >> 3);
#pragma unroll
  for (int ni = 0; ni < 2; ni++) {
    int c = wc_base + wcl + ni * 32 + lrow;
    float b2 = bi2[c];
    float s = 0.0f;
#pragma unroll
    for (int mi = 0; mi < 2; mi++)
#pragma unroll
      for (int r = 0; r < 16; r++) {
        float v = fmaxf(acc[mi][ni][r] + b2, 0.0f);
        bool isdiag = (mi == mi_d) && (r == reg_d) && (lh == half_d);
        s += isdiag ? 0.0f : v;
      }
    s += __shfl_xor(s, 32);
    if (lh == 0) Hsum[(size_t)(b * 64 + iglob) * 512 + c] = s;
  }
}

// ---------------- interactions = (Hsum/63) @ Wi3 + bi3   (2048x512 @ 512x128) ----------------
__global__ __launch_bounds__(256) void k3_kernel(const float* __restrict__ Hsum,
                                                 const float* __restrict__ Wi3,
                                                 const float* __restrict__ bi3,
                                                 float* __restrict__ inter) {
  __shared__ float st[512][20];
  const int t = threadIdx.x;
  const int row0 = blockIdx.x * 16;
  for (int idx = t; idx < 8192; idx += 256) {
    int r = idx >> 9, k = idx & 511;
    st[k][r] = Hsum[(row0 + r) * 512 + k] * (1.0f / 63.0f);
  }
  __syncthreads();
  const int c = t & 63;
  const int rg = t >> 6;
  float a0[4] = {0.f, 0.f, 0.f, 0.f}, a1[4] = {0.f, 0.f, 0.f, 0.f};
#pragma unroll 4
  for (int k = 0; k < 512; k++) {
    float w0 = Wi3[k * 128 + c];
    float w1 = Wi3[k * 128 + 64 + c];
    float4 h = *(const float4*)&st[k][rg * 4];
    a0[0] += h.x * w0; a0[1] += h.y * w0; a0[2] += h.z * w0; a0[3] += h.w * w0;
    a1[0] += h.x * w1; a1[1] += h.y * w1; a1[2] += h.z * w1; a1[3] += h.w * w1;
  }
  float b0 = bi3[c], b1 = bi3[64 + c];
#pragma unroll
  for (int r = 0; r < 4; r++) {
    inter[(row0 + rg * 4 + r) * 128 + c]      = a0[r] + b0;
    inter[(row0 + rg * 4 + r) * 128 + 64 + c] = a1[r] + b1;
  }
}

// ---------------- final combine ----------------
__global__ __launch_bounds__(256) void combine_kernel(const float* __restrict__ S,
                                                      const float* __restrict__ inter,
                                                      const float* __restrict__ coord,
                                                      float* __restrict__ out0) {
  const int i = blockIdx.x * 256 + threadIdx.x;
  float4 s = ((const float4*)S)[i];
  float4 a = ((const float4*)inter)[i];
  float4 c = ((const float4*)coord)[i];
  float4 o;
  o.x = s.x + 0.1f * (a.x + c.x);
  o.y = s.y + 0.1f * (a.y + c.y);
  o.z = s.z + 0.1f * (a.z + c.z);
  o.w = s.w + 0.1f * (a.w + c.w);
  ((float4*)out0)[i] = o;
}

extern "C" void kernel_launch(void* const* d_in, const int* in_sizes, int n_in,
                              void* d_out, int out_size, void* d_ws, size_t ws_size,
                              hipStream_t stream) {
  const float* states = (const float*)d_in[0];
  const float* Wq  = (const float*)d_in[2];
  const float* bq  = (const float*)d_in[3];
  const float* Wi1 = (const float*)d_in[4];
  const float* bi1 = (const float*)d_in[5];
  const float* Wi2 = (const float*)d_in[6];
  const float* bi2 = (const float*)d_in[7];
  const float* Wi3 = (const float*)d_in[8];
  const float* bi3 = (const float*)d_in[9];
  const float* Wc1 = (const float*)d_in[10];
  const float* bc1 = (const float*)d_in[11];
  const float* Wc2 = (const float*)d_in[12];
  const float* bc2 = (const float*)d_in[13];
  const float* Wc3 = (const float*)d_in[14];
  const float* bc3 = (const float*)d_in[15];

  float* out   = (float*)d_out;
  float* out0  = out;            // coordinated_states (B,A,D)
  float* qf    = out + 262144;   // quantum_features (B,F)
  float* inter = out + 524288;   // interactions (B,A,D)
  float* coord = out + 786432;   // coordination (B,A,D)

  char* ws = (char*)d_ws;
  float*          P    = (float*)(ws);                                  // 32MB partials
  float*          U    = (float*)(ws + ((size_t)32 << 20));             // 4MB
  float*          V    = (float*)(ws + ((size_t)36 << 20));             // 4MB
  unsigned short* W2T  = (unsigned short*)(ws + ((size_t)40 << 20));    // 0.5MB
  float*          Hsum = (float*)(ws + ((size_t)41 << 20));             // 4MB
  float*          c1   = (float*)(ws + ((size_t)45 << 20));             // 64KB
  float*          c2   = (float*)(ws + ((size_t)45 << 20) + 65536);     // 64KB

  // prep
  wi2t_kernel<<<dim3(16, 16), 256, 0, stream>>>(Wi2, W2T);
  uv_kernel<<<256, 256, 0, stream>>>(states, Wi1, U, V);

  // quantum features: qf = tanh(states @ Wq + bq)   K=8192 N=8192, KS=32, L=256
  gemm32c<<<dim3(32, 32), 256, 0, stream>>>(states, Wq, P, 8192, 8192, 256);
  reduce_kernel<<<1024, 256, 0, stream>>>(P, bq, qf, 13, 32, 2);

  // interactions
  inter_kernel<<<dim3(4, 32, 32), 256, 0, stream>>>(U, V, W2T, bi1, bi2, Hsum);
  k3_kernel<<<128, 256, 0, stream>>>(Hsum, Wi3, bi3, inter);

  // coordination chain
  // c1 = relu(qf @ Wc1 + bc1): K=8192, N=512, KS=128, L=64
  gemm32c<<<dim3(2, 128), 256, 0, stream>>>(qf, Wc1, P, 8192, 512, 64);
  reduce_kernel<<<64, 256, 0, stream>>>(P, bc1, c1, 9, 128, 1);
  // c2 = relu(c1 @ Wc2 + bc2): K=512, N=512, KS=8, L=64
  gemm32c<<<dim3(2, 8), 256, 0, stream>>>(c1, Wc2, P, 512, 512, 64);
  reduce_kernel<<<64, 256, 0, stream>>>(P, bc2, c2, 9, 8, 1);
  // coord = c2 @ Wc3 + bc3: K=512, N=8192, KS=8, L=64
  gemm32c<<<dim3(32, 8), 256, 0, stream>>>(c2, Wc3, P, 512, 8192, 64);
  reduce_kernel<<<1024, 256, 0, stream>>>(P, bc3, coord, 13, 8, 0);

  // final
  combine_kernel<<<256, 256, 0, stream>>>(states, inter, coord, out0);
}

// Round 4
// 432.088 us; speedup vs baseline: 1.2152x; 1.0618x over previous
//
#include <hip/hip_runtime.h>

typedef __attribute__((ext_vector_type(8))) short bf16x8;
typedef __attribute__((ext_vector_type(16))) float f32x16;

static __device__ __forceinline__ unsigned short f2bf(float x) {
  unsigned int u = __float_as_uint(x);
  return (unsigned short)((u + 0x7FFFu + ((u >> 16) & 1u)) >> 16);
}

// ---------------- Wi2 (512x512 f32) -> W2T bf16 transposed [n][k] ----------------
__global__ __launch_bounds__(256) void wi2t_kernel(const float* __restrict__ Wi2,
                                                   unsigned short* __restrict__ W2T) {
  __shared__ float tile[32][33];
  const int t = threadIdx.x;
  const int bk = blockIdx.x, bn = blockIdx.y;
  const int r = t >> 5, c = t & 31;
#pragma unroll
  for (int p = 0; p < 4; p++) {
    int rr = p * 8 + r;
    tile[rr][c] = Wi2[(bk * 32 + rr) * 512 + bn * 32 + c];
  }
  __syncthreads();
#pragma unroll
  for (int p = 0; p < 4; p++) {
    int rr = p * 8 + r;
    W2T[(bn * 32 + rr) * 512 + bk * 32 + c] = f2bf(tile[c][rr]);
  }
}

// ---------------- U = S @ Wi1[0:128], V = S @ Wi1[128:256]  (2048x128 @ 128x512) ----------------
__global__ __launch_bounds__(256) void uv_kernel(const float* __restrict__ S,
                                                 const float* __restrict__ Wi1,
                                                 float* __restrict__ U, float* __restrict__ V) {
  __shared__ float st[128][12];
  const int t = threadIdx.x;
  const int row0 = blockIdx.x * 8;
  for (int idx = t; idx < 1024; idx += 256) {
    int r = idx >> 7, k = idx & 127;
    st[k][r] = S[(row0 + r) * 128 + k];
  }
  __syncthreads();
  float au0[8], au1[8], av0[8], av1[8];
#pragma unroll
  for (int r = 0; r < 8; r++) { au0[r] = 0.f; au1[r] = 0.f; av0[r] = 0.f; av1[r] = 0.f; }
#pragma unroll 4
  for (int k = 0; k < 128; k++) {
    float wt0 = Wi1[k * 512 + t];
    float wt1 = Wi1[k * 512 + 256 + t];
    float wb0 = Wi1[(k + 128) * 512 + t];
    float wb1 = Wi1[(k + 128) * 512 + 256 + t];
    float4 sA = *(const float4*)&st[k][0];
    float4 sB = *(const float4*)&st[k][4];
    float s8[8] = {sA.x, sA.y, sA.z, sA.w, sB.x, sB.y, sB.z, sB.w};
#pragma unroll
    for (int r = 0; r < 8; r++) {
      au0[r] += s8[r] * wt0;
      au1[r] += s8[r] * wt1;
      av0[r] += s8[r] * wb0;
      av1[r] += s8[r] * wb1;
    }
  }
#pragma unroll
  for (int r = 0; r < 8; r++) {
    U[(row0 + r) * 512 + t]       = au0[r];
    U[(row0 + r) * 512 + 256 + t] = au1[r];
    V[(row0 + r) * 512 + t]       = av0[r];
    V[(row0 + r) * 512 + 256 + t] = av1[r];
  }
}

// ---------------- M=32 GEMM with 4-bank (16-deep) W prefetch ----------------
__device__ __forceinline__ void comp4(const float (*At)[36], int kk, int rg,
                                      const float4 w[4], float acc[8][4]) {
#pragma unroll
  for (int i = 0; i < 4; i++) {
    float4 a0 = *(const float4*)&At[kk + i][rg * 8];
    float4 a1 = *(const float4*)&At[kk + i][rg * 8 + 4];
    float a8[8] = {a0.x, a0.y, a0.z, a0.w, a1.x, a1.y, a1.z, a1.w};
#pragma unroll
    for (int m = 0; m < 8; m++) {
      acc[m][0] += a8[m] * w[i].x;
      acc[m][1] += a8[m] * w[i].y;
      acc[m][2] += a8[m] * w[i].z;
      acc[m][3] += a8[m] * w[i].w;
    }
  }
}

__device__ __forceinline__ void refill4(const float* __restrict__ Wc, int N, int row, float4 w[4]) {
  const float* p = Wc + (size_t)row * N;
#pragma unroll
  for (int j = 0; j < 4; j++) w[j] = *(const float4*)(p + (size_t)j * N);
}

// grid (N/256, KS); block 256. Thread: 8 rows x 4 cols. L % 64 == 0, N % 4 == 0.
__global__ __launch_bounds__(256, 3) void gemm32d(const float* __restrict__ A,
                                                  const float* __restrict__ W,
                                                  float* __restrict__ P,
                                                  int K, int N, int L) {
  __shared__ float At[64][36];
  const int t = threadIdx.x;
  const int nb = blockIdx.x, ks = blockIdx.y;
  const int k0 = ks * L;
  const int rg = t >> 6;                 // wave-uniform row group
  const int c = nb * 256 + (t & 63) * 4;
  float acc[8][4];
#pragma unroll
  for (int m = 0; m < 8; m++) { acc[m][0] = 0.f; acc[m][1] = 0.f; acc[m][2] = 0.f; acc[m][3] = 0.f; }

  const float* Wc = W + c;
  float4 wa[4], wb[4], wc4[4], wd[4];
  refill4(Wc, N, k0, wa);
  refill4(Wc, N, k0 + 4, wb);
  refill4(Wc, N, k0 + 8, wc4);
  refill4(Wc, N, k0 + 12, wd);

  for (int kc = 0; kc < L; kc += 64) {
    __syncthreads();
#pragma unroll
    for (int i = 0; i < 8; i++) {
      int idx = i * 256 + t;
      int k = idx & 63, m = idx >> 6;
      At[k][m] = A[m * K + k0 + kc + k];
    }
    __syncthreads();
#pragma unroll
    for (int kg = 0; kg < 64; kg += 16) {
      const int nx = k0 + kc + kg;
      comp4(At, kg, rg, wa, acc);
      refill4(Wc, N, min(nx + 16, K - 4), wa);
      comp4(At, kg + 4, rg, wb, acc);
      refill4(Wc, N, min(nx + 20, K - 4), wb);
      comp4(At, kg + 8, rg, wc4, acc);
      refill4(Wc, N, min(nx + 24, K - 4), wc4);
      comp4(At, kg + 12, rg, wd, acc);
      refill4(Wc, N, min(nx + 28, K - 4), wd);
    }
  }
  float* Pr = P + (size_t)ks * 32 * N + (size_t)(rg * 8) * N + c;
#pragma unroll
  for (int m = 0; m < 8; m++) {
    float4 o; o.x = acc[m][0]; o.y = acc[m][1]; o.z = acc[m][2]; o.w = acc[m][3];
    *(float4*)&Pr[(size_t)m * N] = o;
  }
}

// ---------------- reduce partials + bias + activation ----------------
__global__ __launch_bounds__(256) void reduce_kernel(const float* __restrict__ P,
                                                     const float* __restrict__ bias,
                                                     float* __restrict__ dst,
                                                     int lnN, int KS, int act) {
  const int idx = blockIdx.x * 256 + threadIdx.x;
  const int N = 1 << lnN;
  const int m = idx >> lnN, n = idx & (N - 1);
  float s = 0.f;
#pragma unroll 8
  for (int p = 0; p < KS; p++) s += P[((size_t)(p * 32 + m) << lnN) + n];
  s += bias[n];
  if (act == 1) s = fmaxf(s, 0.f);
  else if (act == 2) s = tanhf(s);
  dst[idx] = s;
}

// ---------------- interaction core v2: one block per (i-pair, b), all 512 cols ----------------
// Hsum[b,i,:] = sum_{j!=i} relu( relu(U[b,i]+V[b,j]+bi1) @ Wi2 + bi2 )
// block 512 thr = 8 waves = (mg in 0..1) x (ng in 0..3); m=128 rows (ii*64+j), n=512, K=512 in chunks of 64.
__global__ __launch_bounds__(512, 2) void inter2_kernel(const float* __restrict__ U,
                                                        const float* __restrict__ V,
                                                        const unsigned short* __restrict__ W2T,
                                                        const float* __restrict__ bi1,
                                                        const float* __restrict__ bi2,
                                                        float* __restrict__ Hsum) {
  __shared__ __align__(16) unsigned short Albuf[128 * 64]; // h1 tile, swizzled, 16KB
  __shared__ __align__(16) unsigned short Btbuf[512 * 64]; // W2T tile, swizzled, 64KB
  __shared__ float ub[2][512];

  const int t = threadIdx.x;
  const int it = blockIdx.x;   // i-pair 0..31
  const int b  = blockIdx.y;   // batch 0..31

  for (int idx = t; idx < 1024; idx += 512) {
    int ii = idx >> 9, k = idx & 511;
    ub[ii][k] = U[(size_t)(b * 64 + it * 2 + ii) * 512 + k] + bi1[k];
  }

  f32x16 acc[2][4];
#pragma unroll
  for (int mf = 0; mf < 2; mf++)
#pragma unroll
    for (int nf = 0; nf < 4; nf++)
#pragma unroll
      for (int r = 0; r < 16; r++) acc[mf][nf][r] = 0.0f;

  const int w = t >> 6, l = t & 63;
  const int mg = w & 1, ng = w >> 1;
  const int lrow = l & 31, lh = l >> 5;
  const int jst = t & 63;          // staging j row
  const int kst = (t >> 6) * 8;    // staging k base (wave-uniform)

  for (int kc = 0; kc < 512; kc += 64) {
    __syncthreads();
    // ---- stage A = h1 chunk: rows (ii*64+j), local k 0..63 ----
    {
      const float* vp = &V[(size_t)(b * 64 + jst) * 512 + kc + kst];
      float4 v0 = *(const float4*)vp;
      float4 v1 = *(const float4*)(vp + 4);
#pragma unroll
      for (int ii = 0; ii < 2; ii++) {
        float4 u0 = *(const float4*)&ub[ii][kc + kst];
        float4 u1 = *(const float4*)&ub[ii][kc + kst + 4];
        int row = ii * 64 + jst;
        ushort4 p0, p1;
        p0.x = f2bf(fmaxf(v0.x + u0.x, 0.0f));
        p0.y = f2bf(fmaxf(v0.y + u0.y, 0.0f));
        p0.z = f2bf(fmaxf(v0.z + u0.z, 0.0f));
        p0.w = f2bf(fmaxf(v0.w + u0.w, 0.0f));
        p1.x = f2bf(fmaxf(v1.x + u1.x, 0.0f));
        p1.y = f2bf(fmaxf(v1.y + u1.y, 0.0f));
        p1.z = f2bf(fmaxf(v1.z + u1.z, 0.0f));
        p1.w = f2bf(fmaxf(v1.w + u1.w, 0.0f));
        int base = row * 128;
        int sw = (row & 7) << 4;
        *(ushort4*)((char*)Albuf + ((base + kst * 2) ^ sw)) = p0;
        *(ushort4*)((char*)Albuf + ((base + kst * 2 + 8) ^ sw)) = p1;
      }
    }
    // ---- stage B = W2T chunk: n 0..511, local k 0..63 ----
#pragma unroll
    for (int i = 0; i < 16; i++) {
      int idx = i * 512 + t;
      int n = idx >> 4;
      int k4 = (idx & 15) * 4;
      ushort4 u4 = *(const ushort4*)&W2T[(size_t)n * 512 + kc + k4];
      int off = (n * 128 + k4 * 2) ^ ((n & 7) << 4);
      *(ushort4*)((char*)Btbuf + off) = u4;
    }
    __syncthreads();
    // ---- MFMA: 4 k-steps of 16; per wave 2 m-frags x 4 n-frags ----
#pragma unroll
    for (int ks = 0; ks < 4; ks++) {
      const int kbb = ks * 32 + lh * 16;
      bf16x8 afrag[2], bfrag[4];
#pragma unroll
      for (int mf = 0; mf < 2; mf++) {
        int row = mg * 64 + mf * 32 + lrow;
        int off = (row * 128 + kbb) ^ ((row & 7) << 4);
        afrag[mf] = *(const bf16x8*)((const char*)Albuf + off);
      }
#pragma unroll
      for (int nf = 0; nf < 4; nf++) {
        int nr = ng * 128 + nf * 32 + lrow;
        int off = (nr * 128 + kbb) ^ ((nr & 7) << 4);
        bfrag[nf] = *(const bf16x8*)((const char*)Btbuf + off);
      }
#pragma unroll
      for (int mf = 0; mf < 2; mf++)
#pragma unroll
        for (int nf = 0; nf < 4; nf++)
          acc[mf][nf] = __builtin_amdgcn_mfma_f32_32x32x16_bf16(afrag[mf], bfrag[nf], acc[mf][nf], 0, 0, 0);
    }
  }

  // ---- epilogue: relu(+bi2), sum over the wave's 64 rows excluding j==i, write ----
  const int iglob = it * 2 + mg;
  const int mf_d = iglob >> 5;
  const int r5 = iglob & 31;
  const int half_d = (r5 >> 2) & 1;
  const int reg_d = (r5 & 3) + 4 * (r5 >> 3);
#pragma unroll
  for (int nf = 0; nf < 4; nf++) {
    int cidx = ng * 128 + nf * 32 + lrow;
    float b2 = bi2[cidx];
    float s = 0.0f;
#pragma unroll
    for (int mf = 0; mf < 2; mf++)
#pragma unroll
      for (int r = 0; r < 16; r++) {
        float v = fmaxf(acc[mf][nf][r] + b2, 0.0f);
        bool isdiag = (mf == mf_d) && (r == reg_d) && (lh == half_d);
        s += isdiag ? 0.0f : v;
      }
    s += __shfl_xor(s, 32);
    if (lh == 0) Hsum[(size_t)(b * 64 + iglob) * 512 + cidx] = s;
  }
}

// ---------------- interactions = (Hsum/63) @ Wi3 + bi3   (2048x512 @ 512x128) ----------------
__global__ __launch_bounds__(256) void k3_kernel(const float* __restrict__ Hsum,
                                                 const float* __restrict__ Wi3,
                                                 const float* __restrict__ bi3,
                                                 float* __restrict__ inter) {
  __shared__ float st[512][20];
  const int t = threadIdx.x;
  const int row0 = blockIdx.x * 16;
  for (int idx = t; idx < 8192; idx += 256) {
    int r = idx >> 9, k = idx & 511;
    st[k][r] = Hsum[(row0 + r) * 512 + k] * (1.0f / 63.0f);
  }
  __syncthreads();
  const int c = t & 63;
  const int rg = t >> 6;
  float a0[4] = {0.f, 0.f, 0.f, 0.f}, a1[4] = {0.f, 0.f, 0.f, 0.f};
#pragma unroll 4
  for (int k = 0; k < 512; k++) {
    float w0 = Wi3[k * 128 + c];
    float w1 = Wi3[k * 128 + 64 + c];
    float4 h = *(const float4*)&st[k][rg * 4];
    a0[0] += h.x * w0; a0[1] += h.y * w0; a0[2] += h.z * w0; a0[3] += h.w * w0;
    a1[0] += h.x * w1; a1[1] += h.y * w1; a1[2] += h.z * w1; a1[3] += h.w * w1;
  }
  float b0 = bi3[c], b1 = bi3[64 + c];
#pragma unroll
  for (int r = 0; r < 4; r++) {
    inter[(row0 + rg * 4 + r) * 128 + c]      = a0[r] + b0;
    inter[(row0 + rg * 4 + r) * 128 + 64 + c] = a1[r] + b1;
  }
}

// ---------------- final combine ----------------
__global__ __launch_bounds__(256) void combine_kernel(const float* __restrict__ S,
                                                      const float* __restrict__ inter,
                                                      const float* __restrict__ coord,
                                                      float* __restrict__ out0) {
  const int i = blockIdx.x * 256 + threadIdx.x;
  float4 s = ((const float4*)S)[i];
  float4 a = ((const float4*)inter)[i];
  float4 c = ((const float4*)coord)[i];
  float4 o;
  o.x = s.x + 0.1f * (a.x + c.x);
  o.y = s.y + 0.1f * (a.y + c.y);
  o.z = s.z + 0.1f * (a.z + c.z);
  o.w = s.w + 0.1f * (a.w + c.w);
  ((float4*)out0)[i] = o;
}

extern "C" void kernel_launch(void* const* d_in, const int* in_sizes, int n_in,
                              void* d_out, int out_size, void* d_ws, size_t ws_size,
                              hipStream_t stream) {
  const float* states = (const float*)d_in[0];
  const float* Wq  = (const float*)d_in[2];
  const float* bq  = (const float*)d_in[3];
  const float* Wi1 = (const float*)d_in[4];
  const float* bi1 = (const float*)d_in[5];
  const float* Wi2 = (const float*)d_in[6];
  const float* bi2 = (const float*)d_in[7];
  const float* Wi3 = (const float*)d_in[8];
  const float* bi3 = (const float*)d_in[9];
  const float* Wc1 = (const float*)d_in[10];
  const float* bc1 = (const float*)d_in[11];
  const float* Wc2 = (const float*)d_in[12];
  const float* bc2 = (const float*)d_in[13];
  const float* Wc3 = (const float*)d_in[14];
  const float* bc3 = (const float*)d_in[15];

  float* out   = (float*)d_out;
  float* out0  = out;            // coordinated_states (B,A,D)
  float* qf    = out + 262144;   // quantum_features (B,F)
  float* inter = out + 524288;   // interactions (B,A,D)
  float* coord = out + 786432;   // coordination (B,A,D)

  char* ws = (char*)d_ws;
  float*          P    = (float*)(ws);                                  // 32MB partials
  float*          U    = (float*)(ws + ((size_t)32 << 20));             // 4MB
  float*          V    = (float*)(ws + ((size_t)36 << 20));             // 4MB
  unsigned short* W2T  = (unsigned short*)(ws + ((size_t)40 << 20));    // 0.5MB
  float*          Hsum = (float*)(ws + ((size_t)41 << 20));             // 4MB
  float*          c1   = (float*)(ws + ((size_t)45 << 20));             // 64KB
  float*          c2   = (float*)(ws + ((size_t)45 << 20) + 65536);     // 64KB

  // prep
  wi2t_kernel<<<dim3(16, 16), 256, 0, stream>>>(Wi2, W2T);
  uv_kernel<<<256, 256, 0, stream>>>(states, Wi1, U, V);

  // quantum features: qf = tanh(states @ Wq + bq)   K=8192 N=8192, KS=32, L=256
  gemm32d<<<dim3(32, 32), 256, 0, stream>>>(states, Wq, P, 8192, 8192, 256);
  reduce_kernel<<<1024, 256, 0, stream>>>(P, bq, qf, 13, 32, 2);

  // interactions
  inter2_kernel<<<dim3(32, 32), 512, 0, stream>>>(U, V, W2T, bi1, bi2, Hsum);
  k3_kernel<<<128, 256, 0, stream>>>(Hsum, Wi3, bi3, inter);

  // coordination chain
  // c1 = relu(qf @ Wc1 + bc1): K=8192, N=512, KS=128, L=64
  gemm32d<<<dim3(2, 128), 256, 0, stream>>>(qf, Wc1, P, 8192, 512, 64);
  reduce_kernel<<<64, 256, 0, stream>>>(P, bc1, c1, 9, 128, 1);
  // c2 = relu(c1 @ Wc2 + bc2): K=512, N=512, KS=8, L=64
  gemm32d<<<dim3(2, 8), 256, 0, stream>>>(c1, Wc2, P, 512, 512, 64);
  reduce_kernel<<<64, 256, 0, stream>>>(P, bc2, c2, 9, 8, 1);
  // coord = c2 @ Wc3 + bc3: K=512, N=8192, KS=8, L=64
  gemm32d<<<dim3(32, 8), 256, 0, stream>>>(c2, Wc3, P, 512, 8192, 64);
  reduce_kernel<<<1024, 256, 0, stream>>>(P, bc3, coord, 13, 8, 0);

  // final
  combine_kernel<<<256, 256, 0, stream>>>(states, inter, coord, out0);
}

// Round 5
// 335.235 us; speedup vs baseline: 1.5663x; 1.2889x over previous
//
#include <hip/hip_runtime.h>

typedef __attribute__((ext_vector_type(8))) short bf16x8;
typedef __attribute__((ext_vector_type(16))) float f32x16;

static __device__ __forceinline__ unsigned short f2bf(float x) {
  unsigned int u = __float_as_uint(x);
  return (unsigned short)((u + 0x7FFFu + ((u >> 16) & 1u)) >> 16);
}
static __device__ __forceinline__ unsigned int pk2bf(float lo, float hi) {
  return ((unsigned int)f2bf(hi) << 16) | f2bf(lo);
}

// ---------------- f32 -> bf16 bulk convert (one float4 per thread) ----------------
__global__ __launch_bounds__(256) void tobf_kernel(const float* __restrict__ src,
                                                   unsigned short* __restrict__ dst) {
  const int idx = blockIdx.x * 256 + threadIdx.x;
  float4 v = ((const float4*)src)[idx];
  ushort4 o;
  o.x = f2bf(v.x); o.y = f2bf(v.y); o.z = f2bf(v.z); o.w = f2bf(v.w);
  ((ushort4*)dst)[idx] = o;
}

// ---------------- Wi2 (512x512 f32) -> W2T bf16 transposed [n][k] ----------------
__global__ __launch_bounds__(256) void wi2t_kernel(const float* __restrict__ Wi2,
                                                   unsigned short* __restrict__ W2T) {
  __shared__ float tile[32][33];
  const int t = threadIdx.x;
  const int bk = blockIdx.x, bn = blockIdx.y;
  const int r = t >> 5, c = t & 31;
#pragma unroll
  for (int p = 0; p < 4; p++) {
    int rr = p * 8 + r;
    tile[rr][c] = Wi2[(bk * 32 + rr) * 512 + bn * 32 + c];
  }
  __syncthreads();
#pragma unroll
  for (int p = 0; p < 4; p++) {
    int rr = p * 8 + r;
    W2T[(bn * 32 + rr) * 512 + bk * 32 + c] = f2bf(tile[c][rr]);
  }
}

// ---------------- U = S @ Wi1[0:128] + bi1, V = S @ Wi1[128:256] ----------------
__global__ __launch_bounds__(256) void uv_kernel(const float* __restrict__ S,
                                                 const float* __restrict__ Wi1,
                                                 const float* __restrict__ bi1,
                                                 float* __restrict__ U, float* __restrict__ V) {
  __shared__ float st[128][12];
  const int t = threadIdx.x;
  const int row0 = blockIdx.x * 8;
  for (int idx = t; idx < 1024; idx += 256) {
    int r = idx >> 7, k = idx & 127;
    st[k][r] = S[(row0 + r) * 128 + k];
  }
  __syncthreads();
  float au0[8], au1[8], av0[8], av1[8];
#pragma unroll
  for (int r = 0; r < 8; r++) { au0[r] = 0.f; au1[r] = 0.f; av0[r] = 0.f; av1[r] = 0.f; }
#pragma unroll 4
  for (int k = 0; k < 128; k++) {
    float wt0 = Wi1[k * 512 + t];
    float wt1 = Wi1[k * 512 + 256 + t];
    float wb0 = Wi1[(k + 128) * 512 + t];
    float wb1 = Wi1[(k + 128) * 512 + 256 + t];
    float4 sA = *(const float4*)&st[k][0];
    float4 sB = *(const float4*)&st[k][4];
    float s8[8] = {sA.x, sA.y, sA.z, sA.w, sB.x, sB.y, sB.z, sB.w};
#pragma unroll
    for (int r = 0; r < 8; r++) {
      au0[r] += s8[r] * wt0;
      au1[r] += s8[r] * wt1;
      av0[r] += s8[r] * wb0;
      av1[r] += s8[r] * wb1;
    }
  }
  const float b0 = bi1[t], b1 = bi1[256 + t];
#pragma unroll
  for (int r = 0; r < 8; r++) {
    U[(row0 + r) * 512 + t]       = au0[r] + b0;
    U[(row0 + r) * 512 + 256 + t] = au1[r] + b1;
    V[(row0 + r) * 512 + t]       = av0[r];
    V[(row0 + r) * 512 + 256 + t] = av1[r];
  }
}

// ---------------- MFMA M=32 weight-streaming GEMM: P[ks] = Abf[32xK] @ W[k0:k0+L, :] ----------------
// grid (N/128, K/L); block 256 = 4 waves, each wave 32 cols. W loaded f32 -> bf16 in-reg. No barriers in main loop.
__global__ __launch_bounds__(256, 4) void gemmw(const unsigned short* __restrict__ Abf,
                                                const float* __restrict__ W,
                                                float* __restrict__ P,
                                                int K, int N, int L, int l4sh) {
  __shared__ __align__(16) unsigned short As[32 * 512];
  const int t = threadIdx.x;
  const int k0 = blockIdx.y * L;
  const int L4 = L >> 2;
  const int swzm = 2 * L - 1;
  for (int idx = t; idx < (L << 3); idx += 256) {
    int row = idx >> l4sh, k4 = idx & (L4 - 1);
    ushort4 a4 = *(const ushort4*)&Abf[(size_t)row * K + k0 + k4 * 4];
    int off = (row * 2 * L + k4 * 8) ^ (((row & 7) << 4) & swzm);
    *(ushort4*)((char*)As + off) = a4;
  }
  __syncthreads();
  const int lane = t & 63, w = t >> 6;
  const int lrow = lane & 31, lh = lane >> 5;
  const int col = blockIdx.x * 128 + w * 32 + lrow;
  f32x16 acc0, acc1;
#pragma unroll
  for (int r = 0; r < 16; r++) { acc0[r] = 0.f; acc1[r] = 0.f; }
  const float* Wp = W + (size_t)(k0 + lh * 8) * N + col;
  const int aswz = ((lrow & 7) << 4) & swzm;
  const int abase = lrow * 2 * L + lh * 16;
  const int nks = L >> 4;
  int ks = 0;
  for (; ks + 1 < nks; ks += 2) {
    float wv0[8], wv1[8];
#pragma unroll
    for (int jj = 0; jj < 8; jj++) wv0[jj] = Wp[(size_t)(ks * 16 + jj) * N];
#pragma unroll
    for (int jj = 0; jj < 8; jj++) wv1[jj] = Wp[(size_t)(ks * 16 + 16 + jj) * N];
    uint4 b0, b1;
    b0.x = pk2bf(wv0[0], wv0[1]); b0.y = pk2bf(wv0[2], wv0[3]);
    b0.z = pk2bf(wv0[4], wv0[5]); b0.w = pk2bf(wv0[6], wv0[7]);
    b1.x = pk2bf(wv1[0], wv1[1]); b1.y = pk2bf(wv1[2], wv1[3]);
    b1.z = pk2bf(wv1[4], wv1[5]); b1.w = pk2bf(wv1[6], wv1[7]);
    bf16x8 af0 = *(const bf16x8*)((const char*)As + ((abase + ks * 32) ^ aswz));
    bf16x8 af1 = *(const bf16x8*)((const char*)As + ((abase + ks * 32 + 32) ^ aswz));
    acc0 = __builtin_amdgcn_mfma_f32_32x32x16_bf16(af0, *(const bf16x8*)&b0, acc0, 0, 0, 0);
    acc1 = __builtin_amdgcn_mfma_f32_32x32x16_bf16(af1, *(const bf16x8*)&b1, acc1, 0, 0, 0);
  }
  if (ks < nks) {
    float wv0[8];
#pragma unroll
    for (int jj = 0; jj < 8; jj++) wv0[jj] = Wp[(size_t)(ks * 16 + jj) * N];
    uint4 b0;
    b0.x = pk2bf(wv0[0], wv0[1]); b0.y = pk2bf(wv0[2], wv0[3]);
    b0.z = pk2bf(wv0[4], wv0[5]); b0.w = pk2bf(wv0[6], wv0[7]);
    bf16x8 af0 = *(const bf16x8*)((const char*)As + ((abase + ks * 32) ^ aswz));
    acc0 = __builtin_amdgcn_mfma_f32_32x32x16_bf16(af0, *(const bf16x8*)&b0, acc0, 0, 0, 0);
  }
  float* Pr = P + (size_t)blockIdx.y * 32 * N + col;
#pragma unroll
  for (int r = 0; r < 16; r++) {
    int row = (r & 3) + 8 * (r >> 2) + 4 * lh;
    Pr[(size_t)row * N] = acc0[r] + acc1[r];
  }
}

// ---------------- reduce partials + bias + activation (+ optional bf16 copy) ----------------
__global__ __launch_bounds__(256) void reduce_kernel(const float* __restrict__ P,
                                                     const float* __restrict__ bias,
                                                     float* __restrict__ dst,
                                                     unsigned short* __restrict__ dstbf,
                                                     int lnN, int KS, int act, int wbf) {
  const int idx = blockIdx.x * 256 + threadIdx.x;
  const int N = 1 << lnN;
  const int m = idx >> lnN, n = idx & (N - 1);
  float s = 0.f;
#pragma unroll 8
  for (int p = 0; p < KS; p++) s += P[((size_t)(p * 32 + m) << lnN) + n];
  s += bias[n];
  if (act == 1) s = fmaxf(s, 0.f);
  else if (act == 2) s = tanhf(s);
  dst[idx] = s;
  if (wbf) dstbf[idx] = f2bf(s);
}

// ---------------- interaction core v3: persistent-B, on-the-fly h1 ----------------
// Hsum[b,i,:] = sum_{j!=i} relu( relu(U'[b,i]+V[b,j]) @ Wi2 + bi2 ),  U' = U + bi1
// grid (4 nq, 256); block 512 thr = 8 waves = 2 mg (i within pair) x 4 ng (32-col groups).
// LDS: Bt = W2T[nq*128..+128][0..512] bf16 (128KB, staged once), Ab = h1[128][64] bf16 (16KB).
__global__ __launch_bounds__(512, 2) void inter3_kernel(const float* __restrict__ U,
                                                        const float* __restrict__ V,
                                                        const unsigned short* __restrict__ W2T,
                                                        const float* __restrict__ bi2,
                                                        float* __restrict__ Hsum) {
  __shared__ __align__(16) unsigned short Bt[128 * 512]; // 128KB
  __shared__ __align__(16) unsigned short Ab[128 * 64];  // 16KB
  const int t = threadIdx.x;
  const int nq = blockIdx.x;

  { // stage B once (coalesced along k, XOR-swizzled rows)
    const unsigned short* src = W2T + (size_t)nq * 128 * 512;
#pragma unroll
    for (int i = 0; i < 32; i++) {
      int idx = i * 512 + t;
      int n = idx >> 7, k4 = idx & 127;
      ushort4 u4 = *(const ushort4*)&src[(size_t)n * 512 + k4 * 4];
      int off = (n * 1024 + k4 * 8) ^ ((n & 7) << 4);
      *(ushort4*)((char*)Bt + off) = u4;
    }
  }
  __syncthreads();

  const int w = t >> 6, lane = t & 63;
  const int mg = w & 1, ng = w >> 1;
  const int lrow = lane & 31, lh = lane >> 5;
  const int jg = t >> 3;        // A-gen: j row 0..63
  const int k8 = (t & 7) * 8;   // A-gen: k base within chunk

  const int cidx = nq * 128 + ng * 32 + lrow;
  const float b2 = bi2[cidx];

  for (int s = 0; s < 4; s++) {
    const int tid = blockIdx.y * 4 + s;
    const int b = tid >> 5, it = tid & 31;
    f32x16 acc0, acc1;
#pragma unroll
    for (int r = 0; r < 16; r++) { acc0[r] = 0.f; acc1[r] = 0.f; }
    const float* Vb = V + ((size_t)(b * 64 + jg)) * 512;
    const float* Ub = U + ((size_t)(b * 64 + it * 2)) * 512;

    for (int kc = 0; kc < 512; kc += 64) {
      __syncthreads();
      // ---- A-gen: h1 chunk 128 rows x 64 k ----
      float4 v0 = *(const float4*)&Vb[kc + k8];
      float4 v1 = *(const float4*)&Vb[kc + k8 + 4];
#pragma unroll
      for (int ii = 0; ii < 2; ii++) {
        float4 u0 = *(const float4*)&Ub[(size_t)ii * 512 + kc + k8];
        float4 u1 = *(const float4*)&Ub[(size_t)ii * 512 + kc + k8 + 4];
        uint4 pk;
        pk.x = pk2bf(fmaxf(v0.x + u0.x, 0.f), fmaxf(v0.y + u0.y, 0.f));
        pk.y = pk2bf(fmaxf(v0.z + u0.z, 0.f), fmaxf(v0.w + u0.w, 0.f));
        pk.z = pk2bf(fmaxf(v1.x + u1.x, 0.f), fmaxf(v1.y + u1.y, 0.f));
        pk.w = pk2bf(fmaxf(v1.z + u1.z, 0.f), fmaxf(v1.w + u1.w, 0.f));
        int row = ii * 64 + jg;
        int off = (row * 128 + k8 * 2) ^ ((row & 7) << 4);
        *(uint4*)((char*)Ab + off) = pk;
      }
      __syncthreads();
      // ---- MFMA: 4 ksteps of 16 ----
#pragma unroll
      for (int ks = 0; ks < 4; ks++) {
        const int kb = ks * 16 + lh * 8;
        int r0 = mg * 64 + lrow;
        int r1 = mg * 64 + 32 + lrow;
        bf16x8 af0 = *(const bf16x8*)((const char*)Ab + ((r0 * 128 + kb * 2) ^ ((r0 & 7) << 4)));
        bf16x8 af1 = *(const bf16x8*)((const char*)Ab + ((r1 * 128 + kb * 2) ^ ((r1 & 7) << 4)));
        int nr = ng * 32 + lrow;
        bf16x8 bfr = *(const bf16x8*)((const char*)Bt + ((nr * 1024 + (kc + kb) * 2) ^ ((nr & 7) << 4)));
        acc0 = __builtin_amdgcn_mfma_f32_32x32x16_bf16(af0, bfr, acc0, 0, 0, 0);
        acc1 = __builtin_amdgcn_mfma_f32_32x32x16_bf16(af1, bfr, acc1, 0, 0, 0);
      }
    }
    // ---- epilogue: relu(+bi2), sum 64 j excluding j==i, write ----
    const int iag = it * 2 + mg;
    const int mf_d = iag >> 5;
    const int r5 = iag & 31;
    const int half_d = (r5 >> 2) & 1;
    const int reg_d = (r5 & 3) + 4 * (r5 >> 3);
    float ssum = 0.f;
#pragma unroll
    for (int r = 0; r < 16; r++) {
      float v0 = fmaxf(acc0[r] + b2, 0.f);
      float v1 = fmaxf(acc1[r] + b2, 0.f);
      bool d0 = (0 == mf_d) && (r == reg_d) && (lh == half_d);
      bool d1 = (1 == mf_d) && (r == reg_d) && (lh == half_d);
      ssum += (d0 ? 0.f : v0) + (d1 ? 0.f : v1);
    }
    ssum += __shfl_xor(ssum, 32);
    if (lh == 0) Hsum[((size_t)(b * 64 + iag)) * 512 + cidx] = ssum;
  }
}

// ---------------- interactions = (Hsum/63) @ Wi3 + bi3   (2048x512 @ 512x128) ----------------
__global__ __launch_bounds__(256) void k3_kernel(const float* __restrict__ Hsum,
                                                 const float* __restrict__ Wi3,
                                                 const float* __restrict__ bi3,
                                                 float* __restrict__ inter) {
  __shared__ float st[512][20];
  const int t = threadIdx.x;
  const int row0 = blockIdx.x * 16;
  for (int idx = t; idx < 8192; idx += 256) {
    int r = idx >> 9, k = idx & 511;
    st[k][r] = Hsum[(row0 + r) * 512 + k] * (1.0f / 63.0f);
  }
  __syncthreads();
  const int c = t & 63;
  const int rg = t >> 6;
  float a0[4] = {0.f, 0.f, 0.f, 0.f}, a1[4] = {0.f, 0.f, 0.f, 0.f};
#pragma unroll 4
  for (int k = 0; k < 512; k++) {
    float w0 = Wi3[k * 128 + c];
    float w1 = Wi3[k * 128 + 64 + c];
    float4 h = *(const float4*)&st[k][rg * 4];
    a0[0] += h.x * w0; a0[1] += h.y * w0; a0[2] += h.z * w0; a0[3] += h.w * w0;
    a1[0] += h.x * w1; a1[1] += h.y * w1; a1[2] += h.z * w1; a1[3] += h.w * w1;
  }
  float b0 = bi3[c], b1 = bi3[64 + c];
#pragma unroll
  for (int r = 0; r < 4; r++) {
    inter[(row0 + rg * 4 + r) * 128 + c]      = a0[r] + b0;
    inter[(row0 + rg * 4 + r) * 128 + 64 + c] = a1[r] + b1;
  }
}

// ---------------- final combine ----------------
__global__ __launch_bounds__(256) void combine_kernel(const float* __restrict__ S,
                                                      const float* __restrict__ inter,
                                                      const float* __restrict__ coord,
                                                      float* __restrict__ out0) {
  const int i = blockIdx.x * 256 + threadIdx.x;
  float4 s = ((const float4*)S)[i];
  float4 a = ((const float4*)inter)[i];
  float4 c = ((const float4*)coord)[i];
  float4 o;
  o.x = s.x + 0.1f * (a.x + c.x);
  o.y = s.y + 0.1f * (a.y + c.y);
  o.z = s.z + 0.1f * (a.z + c.z);
  o.w = s.w + 0.1f * (a.w + c.w);
  ((float4*)out0)[i] = o;
}

extern "C" void kernel_launch(void* const* d_in, const int* in_sizes, int n_in,
                              void* d_out, int out_size, void* d_ws, size_t ws_size,
                              hipStream_t stream) {
  const float* states = (const float*)d_in[0];
  const float* Wq  = (const float*)d_in[2];
  const float* bq  = (const float*)d_in[3];
  const float* Wi1 = (const float*)d_in[4];
  const float* bi1 = (const float*)d_in[5];
  const float* Wi2 = (const float*)d_in[6];
  const float* bi2 = (const float*)d_in[7];
  const float* Wi3 = (const float*)d_in[8];
  const float* bi3 = (const float*)d_in[9];
  const float* Wc1 = (const float*)d_in[10];
  const float* bc1 = (const float*)d_in[11];
  const float* Wc2 = (const float*)d_in[12];
  const float* bc2 = (const float*)d_in[13];
  const float* Wc3 = (const float*)d_in[14];
  const float* bc3 = (const float*)d_in[15];

  float* out   = (float*)d_out;
  float* out0  = out;            // coordinated_states (B,A,D)
  float* qf    = out + 262144;   // quantum_features (B,F)
  float* inter = out + 524288;   // interactions (B,A,D)
  float* coord = out + 786432;   // coordination (B,A,D)

  char* ws = (char*)d_ws;
  float*          P    = (float*)(ws);                                   // 16MB max partials
  float*          U    = (float*)(ws + ((size_t)16 << 20));              // 4MB (includes +bi1)
  float*          V    = (float*)(ws + ((size_t)20 << 20));              // 4MB
  unsigned short* W2T  = (unsigned short*)(ws + ((size_t)24 << 20));     // 0.5MB
  float*          Hsum = (float*)(ws + ((size_t)25 << 20));              // 4MB
  unsigned short* Sbf  = (unsigned short*)(ws + ((size_t)29 << 20));     // 0.5MB
  unsigned short* qfbf = (unsigned short*)(ws + ((size_t)30 << 20));     // 0.5MB
  float*          c1   = (float*)(ws + ((size_t)31 << 20));              // 64KB
  float*          c2   = (float*)(ws + ((size_t)31 << 20) + (1 << 16));  // 64KB
  unsigned short* c1bf = (unsigned short*)(ws + ((size_t)31 << 20) + (2 << 16)); // 32KB
  unsigned short* c2bf = (unsigned short*)(ws + ((size_t)31 << 20) + (3 << 16)); // 32KB

  // prep
  tobf_kernel<<<256, 256, 0, stream>>>(states, Sbf);
  wi2t_kernel<<<dim3(16, 16), 256, 0, stream>>>(Wi2, W2T);
  uv_kernel<<<256, 256, 0, stream>>>(states, Wi1, bi1, U, V);

  // quantum features: qf = tanh(states @ Wq + bq)   K=8192 N=8192, KS=16, L=512
  gemmw<<<dim3(64, 16), 256, 0, stream>>>(Sbf, Wq, P, 8192, 8192, 512, 7);
  reduce_kernel<<<1024, 256, 0, stream>>>(P, bq, qf, qfbf, 13, 16, 2, 1);

  // interactions
  inter3_kernel<<<dim3(4, 256), 512, 0, stream>>>(U, V, W2T, bi2, Hsum);
  k3_kernel<<<128, 256, 0, stream>>>(Hsum, Wi3, bi3, inter);

  // coordination chain
  // c1 = relu(qf @ Wc1 + bc1): K=8192, N=512, L=128, KS=64
  gemmw<<<dim3(4, 64), 256, 0, stream>>>(qfbf, Wc1, P, 8192, 512, 128, 5);
  reduce_kernel<<<64, 256, 0, stream>>>(P, bc1, c1, c1bf, 9, 64, 1, 1);
  // c2 = relu(c1 @ Wc2 + bc2): K=512, N=512, L=16, KS=32
  gemmw<<<dim3(4, 32), 256, 0, stream>>>(c1bf, Wc2, P, 512, 512, 16, 2);
  reduce_kernel<<<64, 256, 0, stream>>>(P, bc2, c2, c2bf, 9, 32, 1, 1);
  // coord = c2 @ Wc3 + bc3: K=512, N=8192, L=64, KS=8
  gemmw<<<dim3(64, 8), 256, 0, stream>>>(c2bf, Wc3, P, 512, 8192, 64, 4);
  reduce_kernel<<<1024, 256, 0, stream>>>(P, bc3, coord, qfbf, 13, 8, 0, 0);

  // final
  combine_kernel<<<256, 256, 0, stream>>>(states, inter, coord, out0);
}

// Round 7
// 251.285 us; speedup vs baseline: 2.0896x; 1.3341x over previous
//
#include <hip/hip_runtime.h>

typedef __attribute__((ext_vector_type(8))) short bf16x8;
typedef __attribute__((ext_vector_type(16))) float f32x16;
typedef _Float16 f16;
typedef __attribute__((ext_vector_type(8))) _Float16 f16x8;

static __device__ __forceinline__ unsigned short f2bf(float x) {
  unsigned int u = __float_as_uint(x);
  return (unsigned short)((u + 0x7FFFu + ((u >> 16) & 1u)) >> 16);
}
static __device__ __forceinline__ unsigned int pk2bf(float lo, float hi) {
  return ((unsigned int)f2bf(hi) << 16) | f2bf(lo);
}

static __device__ __forceinline__ f16x8 relu8(f16x8 x) {
  f16x8 z = {0, 0, 0, 0, 0, 0, 0, 0};
  return __builtin_elementwise_max(x, z);
}

// ---------------- f32 -> bf16 bulk convert ----------------
__global__ __launch_bounds__(256) void tobf_kernel(const float* __restrict__ src,
                                                   unsigned short* __restrict__ dst) {
  const int idx = blockIdx.x * 256 + threadIdx.x;
  float4 v = ((const float4*)src)[idx];
  ushort4 o;
  o.x = f2bf(v.x); o.y = f2bf(v.y); o.z = f2bf(v.z); o.w = f2bf(v.w);
  ((ushort4*)dst)[idx] = o;
}

// ---------------- Wi2 (512x512 f32) -> W2h f16 transposed [n][k] ----------------
__global__ __launch_bounds__(256) void w2h_kernel(const float* __restrict__ Wi2,
                                                  f16* __restrict__ W2h) {
  __shared__ float tile[32][33];
  const int t = threadIdx.x;
  const int bk = blockIdx.x, bn = blockIdx.y;
  const int r = t >> 5, c = t & 31;
#pragma unroll
  for (int p = 0; p < 4; p++) {
    int rr = p * 8 + r;
    tile[rr][c] = Wi2[(bk * 32 + rr) * 512 + bn * 32 + c];
  }
  __syncthreads();
#pragma unroll
  for (int p = 0; p < 4; p++) {
    int rr = p * 8 + r;
    W2h[(bn * 32 + rr) * 512 + bk * 32 + c] = (f16)tile[c][rr];
  }
}

// ---------------- Uh = f16(S @ Wi1[0:128] + bi1), Vh = f16(S @ Wi1[128:256]) ----------------
__global__ __launch_bounds__(256) void uvh_kernel(const float* __restrict__ S,
                                                  const float* __restrict__ Wi1,
                                                  const float* __restrict__ bi1,
                                                  f16* __restrict__ Uh, f16* __restrict__ Vh) {
  __shared__ float st[128][12];
  const int t = threadIdx.x;
  const int row0 = blockIdx.x * 8;
  for (int idx = t; idx < 1024; idx += 256) {
    int r = idx >> 7, k = idx & 127;
    st[k][r] = S[(row0 + r) * 128 + k];
  }
  __syncthreads();
  float au0[8], au1[8], av0[8], av1[8];
#pragma unroll
  for (int r = 0; r < 8; r++) { au0[r] = 0.f; au1[r] = 0.f; av0[r] = 0.f; av1[r] = 0.f; }
#pragma unroll 4
  for (int k = 0; k < 128; k++) {
    float wt0 = Wi1[k * 512 + t];
    float wt1 = Wi1[k * 512 + 256 + t];
    float wb0 = Wi1[(k + 128) * 512 + t];
    float wb1 = Wi1[(k + 128) * 512 + 256 + t];
    float4 sA = *(const float4*)&st[k][0];
    float4 sB = *(const float4*)&st[k][4];
    float s8[8] = {sA.x, sA.y, sA.z, sA.w, sB.x, sB.y, sB.z, sB.w};
#pragma unroll
    for (int r = 0; r < 8; r++) {
      au0[r] += s8[r] * wt0;
      au1[r] += s8[r] * wt1;
      av0[r] += s8[r] * wb0;
      av1[r] += s8[r] * wb1;
    }
  }
  const float b0 = bi1[t], b1 = bi1[256 + t];
#pragma unroll
  for (int r = 0; r < 8; r++) {
    Uh[(row0 + r) * 512 + t]       = (f16)(au0[r] + b0);
    Uh[(row0 + r) * 512 + 256 + t] = (f16)(au1[r] + b1);
    Vh[(row0 + r) * 512 + t]       = (f16)av0[r];
    Vh[(row0 + r) * 512 + 256 + t] = (f16)av1[r];
  }
}

// ---------------- MFMA M=32 weight-streaming GEMM: P[ks] = Abf[32xK] @ W[k0:k0+L, :] ----------------
__global__ __launch_bounds__(256, 4) void gemmw(const unsigned short* __restrict__ Abf,
                                                const float* __restrict__ W,
                                                float* __restrict__ P,
                                                int K, int N, int L, int l4sh) {
  __shared__ __align__(16) unsigned short As[32 * 512];
  const int t = threadIdx.x;
  const int k0 = blockIdx.y * L;
  const int L4 = L >> 2;
  const int swzm = 2 * L - 1;
  for (int idx = t; idx < (L << 3); idx += 256) {
    int row = idx >> l4sh, k4 = idx & (L4 - 1);
    ushort4 a4 = *(const ushort4*)&Abf[(size_t)row * K + k0 + k4 * 4];
    int off = (row * 2 * L + k4 * 8) ^ (((row & 7) << 4) & swzm);
    *(ushort4*)((char*)As + off) = a4;
  }
  __syncthreads();
  const int lane = t & 63, w = t >> 6;
  const int lrow = lane & 31, lh = lane >> 5;
  const int col = blockIdx.x * 128 + w * 32 + lrow;
  f32x16 acc0, acc1;
#pragma unroll
  for (int r = 0; r < 16; r++) { acc0[r] = 0.f; acc1[r] = 0.f; }
  const float* Wp = W + (size_t)(k0 + lh * 8) * N + col;
  const int aswz = ((lrow & 7) << 4) & swzm;
  const int abase = lrow * 2 * L + lh * 16;
  const int nks = L >> 4;
  int ks = 0;
  for (; ks + 1 < nks; ks += 2) {
    float wv0[8], wv1[8];
#pragma unroll
    for (int jj = 0; jj < 8; jj++) wv0[jj] = Wp[(size_t)(ks * 16 + jj) * N];
#pragma unroll
    for (int jj = 0; jj < 8; jj++) wv1[jj] = Wp[(size_t)(ks * 16 + 16 + jj) * N];
    uint4 b0, b1;
    b0.x = pk2bf(wv0[0], wv0[1]); b0.y = pk2bf(wv0[2], wv0[3]);
    b0.z = pk2bf(wv0[4], wv0[5]); b0.w = pk2bf(wv0[6], wv0[7]);
    b1.x = pk2bf(wv1[0], wv1[1]); b1.y = pk2bf(wv1[2], wv1[3]);
    b1.z = pk2bf(wv1[4], wv1[5]); b1.w = pk2bf(wv1[6], wv1[7]);
    bf16x8 af0 = *(const bf16x8*)((const char*)As + ((abase + ks * 32) ^ aswz));
    bf16x8 af1 = *(const bf16x8*)((const char*)As + ((abase + ks * 32 + 32) ^ aswz));
    acc0 = __builtin_amdgcn_mfma_f32_32x32x16_bf16(af0, *(const bf16x8*)&b0, acc0, 0, 0, 0);
    acc1 = __builtin_amdgcn_mfma_f32_32x32x16_bf16(af1, *(const bf16x8*)&b1, acc1, 0, 0, 0);
  }
  if (ks < nks) {
    float wv0[8];
#pragma unroll
    for (int jj = 0; jj < 8; jj++) wv0[jj] = Wp[(size_t)(ks * 16 + jj) * N];
    uint4 b0;
    b0.x = pk2bf(wv0[0], wv0[1]); b0.y = pk2bf(wv0[2], wv0[3]);
    b0.z = pk2bf(wv0[4], wv0[5]); b0.w = pk2bf(wv0[6], wv0[7]);
    bf16x8 af0 = *(const bf16x8*)((const char*)As + ((abase + ks * 32) ^ aswz));
    acc0 = __builtin_amdgcn_mfma_f32_32x32x16_bf16(af0, *(const bf16x8*)&b0, acc0, 0, 0, 0);
  }
  float* Pr = P + (size_t)blockIdx.y * 32 * N + col;
#pragma unroll
  for (int r = 0; r < 16; r++) {
    int row = (r & 3) + 8 * (r >> 2) + 4 * lh;
    Pr[(size_t)row * N] = acc0[r] + acc1[r];
  }
}

// ---------------- reduce partials + bias + activation (+ optional bf16 copy) ----------------
__global__ __launch_bounds__(256) void reduce_kernel(const float* __restrict__ P,
                                                     const float* __restrict__ bias,
                                                     float* __restrict__ dst,
                                                     unsigned short* __restrict__ dstbf,
                                                     int lnN, int KS, int act, int wbf) {
  const int idx = blockIdx.x * 256 + threadIdx.x;
  const int N = 1 << lnN;
  const int m = idx >> lnN, n = idx & (N - 1);
  float s = 0.f;
#pragma unroll 8
  for (int p = 0; p < KS; p++) s += P[((size_t)(p * 32 + m) << lnN) + n];
  s += bias[n];
  if (act == 1) s = fmaxf(s, 0.f);
  else if (act == 2) s = tanhf(s);
  dst[idx] = s;
  if (wbf) dstbf[idx] = f2bf(s);
}

// ---------------- interaction core v4: register-A f16, persistent-B LDS, no inner barriers ----------------
// Hsum[b,i,:] = sum_{j!=i} relu( relu(Uh[b,i]+Vh[b,j]) @ Wi2 + bi2 )
// grid (4 nq, 64); block 512 = 8 waves = 4 tile-groups x 2 n-groups. Per wave: 4 m-frags x 2 n-frags.
__global__ __launch_bounds__(512, 2) void inter4_kernel(const f16* __restrict__ Uh,
                                                        const f16* __restrict__ Vh,
                                                        const f16* __restrict__ W2h,
                                                        const float* __restrict__ bi2,
                                                        float* __restrict__ Hsum) {
  __shared__ __align__(16) f16 Bt[128 * 512]; // 128KB, swizzled
  const int t = threadIdx.x;
  const int nq = blockIdx.x;

  // stage B slice once: rows nq*128..+128 of W2h [n][k]
#pragma unroll
  for (int i = 0; i < 16; i++) {
    int idx = i * 512 + t;
    int n = idx >> 6, ch = idx & 63;
    f16x8 w8 = *(const f16x8*)&W2h[(size_t)(nq * 128 + n) * 512 + ch * 8];
    int off = (n * 1024 + ch * 16) ^ ((n & 15) << 4);
    *(f16x8*)((char*)Bt + off) = w8;
  }
  __syncthreads();

  const int w = t >> 6, lane = t & 63;
  const int tg = w >> 1, ng = w & 1;
  const int lrow = lane & 31, lh = lane >> 5;
  const int nr0 = ng * 64 + lrow;
  const int nr1 = nr0 + 32;
  const int base0 = nr0 * 1024 + lh * 16;
  const int base1 = nr1 * 1024 + lh * 16;
  const int swz0 = (nr0 & 15) << 4;
  const int swz1 = (nr1 & 15) << 4;
  const char* Btc = (const char*)Bt;

  for (int s = 0; s < 4; s++) {
    const int tid = blockIdx.y * 16 + tg * 4 + s;
    const int b = tid >> 5, it = tid & 31;
    const f16* Vb0 = Vh + (size_t)(b * 64 + lrow) * 512 + lh * 8;
    const f16* Vb1 = Vb0 + (size_t)32 * 512;
    const f16* Ub0 = Uh + (size_t)(b * 64 + it * 2) * 512 + lh * 8;
    const f16* Ub1 = Ub0 + 512;

    f32x16 acc00, acc01, acc10, acc11, acc20, acc21, acc30, acc31;
#pragma unroll
    for (int r = 0; r < 16; r++) {
      acc00[r] = 0.f; acc01[r] = 0.f; acc10[r] = 0.f; acc11[r] = 0.f;
      acc20[r] = 0.f; acc21[r] = 0.f; acc30[r] = 0.f; acc31[r] = 0.f;
    }

    f16x8 v0 = *(const f16x8*)(Vb0);
    f16x8 v1 = *(const f16x8*)(Vb1);
    f16x8 u0 = *(const f16x8*)(Ub0);
    f16x8 u1 = *(const f16x8*)(Ub1);
    f16x8 bf0 = *(const f16x8*)(Btc + (base0 ^ swz0));
    f16x8 bf1 = *(const f16x8*)(Btc + (base1 ^ swz1));

#pragma unroll 2
    for (int kc = 0; kc < 512; kc += 16) {
      const int kn = (kc + 16) & 511;
      // prefetch next k-step (global: L1/L2-resident; LDS: no barrier needed)
      f16x8 v0n = *(const f16x8*)(Vb0 + kn);
      f16x8 v1n = *(const f16x8*)(Vb1 + kn);
      f16x8 u0n = *(const f16x8*)(Ub0 + kn);
      f16x8 u1n = *(const f16x8*)(Ub1 + kn);
      f16x8 bf0n = *(const f16x8*)(Btc + ((base0 + kn * 2) ^ swz0));
      f16x8 bf1n = *(const f16x8*)(Btc + ((base1 + kn * 2) ^ swz1));
      // A-frags in registers (lane = j-row, lh = k-half) — matches MFMA A layout
      f16x8 a0 = relu8(v0 + u0);   // ii=0, j 0..31
      f16x8 a1 = relu8(v1 + u0);   // ii=0, j 32..63
      f16x8 a2 = relu8(v0 + u1);   // ii=1, j 0..31
      f16x8 a3 = relu8(v1 + u1);   // ii=1, j 32..63
      acc00 = __builtin_amdgcn_mfma_f32_32x32x16_f16(a0, bf0, acc00, 0, 0, 0);
      acc01 = __builtin_amdgcn_mfma_f32_32x32x16_f16(a0, bf1, acc01, 0, 0, 0);
      acc10 = __builtin_amdgcn_mfma_f32_32x32x16_f16(a1, bf0, acc10, 0, 0, 0);
      acc11 = __builtin_amdgcn_mfma_f32_32x32x16_f16(a1, bf1, acc11, 0, 0, 0);
      acc20 = __builtin_amdgcn_mfma_f32_32x32x16_f16(a2, bf0, acc20, 0, 0, 0);
      acc21 = __builtin_amdgcn_mfma_f32_32x32x16_f16(a2, bf1, acc21, 0, 0, 0);
      acc30 = __builtin_amdgcn_mfma_f32_32x32x16_f16(a3, bf0, acc30, 0, 0, 0);
      acc31 = __builtin_amdgcn_mfma_f32_32x32x16_f16(a3, bf1, acc31, 0, 0, 0);
      v0 = v0n; v1 = v1n; u0 = u0n; u1 = u1n; bf0 = bf0n; bf1 = bf1n;
    }

    // epilogue: relu(+bi2), sum over 64 j excluding j == iglob, write Hsum
#define EPI(II, NF, ACCA, ACCB)                                                \
    {                                                                          \
      const int iglob = it * 2 + (II);                                         \
      const int mh_d = iglob >> 5;                                             \
      const int rd = iglob & 31;                                               \
      const int lh_d = (rd >> 2) & 1;                                          \
      const int r_d = (rd & 3) + 4 * (rd >> 3);                                \
      const int col = nq * 128 + ng * 64 + (NF)*32 + lrow;                     \
      const float b2 = bi2[col];                                               \
      float ssum = 0.f;                                                        \
      _Pragma("unroll")                                                        \
      for (int r = 0; r < 16; r++) {                                           \
        float x0 = fmaxf(ACCA[r] + b2, 0.f);                                   \
        float x1 = fmaxf(ACCB[r] + b2, 0.f);                                   \
        if (mh_d == 0 && r == r_d && lh == lh_d) x0 = 0.f;                     \
        if (mh_d == 1 && r == r_d && lh == lh_d) x1 = 0.f;                     \
        ssum += x0 + x1;                                                       \
      }                                                                        \
      ssum += __shfl_xor(ssum, 32);                                            \
      if (lh == 0) Hsum[(size_t)(b * 64 + iglob) * 512 + col] = ssum;          \
    }
    EPI(0, 0, acc00, acc10)
    EPI(0, 1, acc01, acc11)
    EPI(1, 0, acc20, acc30)
    EPI(1, 1, acc21, acc31)
#undef EPI
  }
}

// ---------------- interactions = (Hsum/63) @ Wi3 + bi3   (2048x512 @ 512x128) ----------------
__global__ __launch_bounds__(256) void k3_kernel(const float* __restrict__ Hsum,
                                                 const float* __restrict__ Wi3,
                                                 const float* __restrict__ bi3,
                                                 float* __restrict__ inter) {
  __shared__ float st[512][20];
  const int t = threadIdx.x;
  const int row0 = blockIdx.x * 16;
  for (int idx = t; idx < 8192; idx += 256) {
    int r = idx >> 9, k = idx & 511;
    st[k][r] = Hsum[(row0 + r) * 512 + k] * (1.0f / 63.0f);
  }
  __syncthreads();
  const int c = t & 63;
  const int rg = t >> 6;
  float a0[4] = {0.f, 0.f, 0.f, 0.f}, a1[4] = {0.f, 0.f, 0.f, 0.f};
#pragma unroll 4
  for (int k = 0; k < 512; k++) {
    float w0 = Wi3[k * 128 + c];
    float w1 = Wi3[k * 128 + 64 + c];
    float4 h = *(const float4*)&st[k][rg * 4];
    a0[0] += h.x * w0; a0[1] += h.y * w0; a0[2] += h.z * w0; a0[3] += h.w * w0;
    a1[0] += h.x * w1; a1[1] += h.y * w1; a1[2] += h.z * w1; a1[3] += h.w * w1;
  }
  float b0 = bi3[c], b1 = bi3[64 + c];
#pragma unroll
  for (int r = 0; r < 4; r++) {
    inter[(row0 + rg * 4 + r) * 128 + c]      = a0[r] + b0;
    inter[(row0 + rg * 4 + r) * 128 + 64 + c] = a1[r] + b1;
  }
}

// ---------------- final combine ----------------
__global__ __launch_bounds__(256) void combine_kernel(const float* __restrict__ S,
                                                      const float* __restrict__ inter,
                                                      const float* __restrict__ coord,
                                                      float* __restrict__ out0) {
  const int i = blockIdx.x * 256 + threadIdx.x;
  float4 s = ((const float4*)S)[i];
  float4 a = ((const float4*)inter)[i];
  float4 c = ((const float4*)coord)[i];
  float4 o;
  o.x = s.x + 0.1f * (a.x + c.x);
  o.y = s.y + 0.1f * (a.y + c.y);
  o.z = s.z + 0.1f * (a.z + c.z);
  o.w = s.w + 0.1f * (a.w + c.w);
  ((float4*)out0)[i] = o;
}

extern "C" void kernel_launch(void* const* d_in, const int* in_sizes, int n_in,
                              void* d_out, int out_size, void* d_ws, size_t ws_size,
                              hipStream_t stream) {
  const float* states = (const float*)d_in[0];
  const float* Wq  = (const float*)d_in[2];
  const float* bq  = (const float*)d_in[3];
  const float* Wi1 = (const float*)d_in[4];
  const float* bi1 = (const float*)d_in[5];
  const float* Wi2 = (const float*)d_in[6];
  const float* bi2 = (const float*)d_in[7];
  const float* Wi3 = (const float*)d_in[8];
  const float* bi3 = (const float*)d_in[9];
  const float* Wc1 = (const float*)d_in[10];
  const float* bc1 = (const float*)d_in[11];
  const float* Wc2 = (const float*)d_in[12];
  const float* bc2 = (const float*)d_in[13];
  const float* Wc3 = (const float*)d_in[14];
  const float* bc3 = (const float*)d_in[15];

  float* out   = (float*)d_out;
  float* out0  = out;            // coordinated_states (B,A,D)
  float* qf    = out + 262144;   // quantum_features (B,F)
  float* inter = out + 524288;   // interactions (B,A,D)
  float* coord = out + 786432;   // coordination (B,A,D)

  char* ws = (char*)d_ws;
  float*          P    = (float*)(ws);                                   // 16MB partials
  f16*            Uh   = (f16*)(ws + ((size_t)16 << 20));                // 2MB (+pad)
  f16*            Vh   = (f16*)(ws + ((size_t)19 << 20));                // 2MB (+pad)
  f16*            W2h  = (f16*)(ws + ((size_t)22 << 20));                // 0.5MB
  float*          Hsum = (float*)(ws + ((size_t)23 << 20));              // 4MB
  unsigned short* Sbf  = (unsigned short*)(ws + ((size_t)27 << 20));     // 0.5MB
  unsigned short* qfbf = (unsigned short*)(ws + ((size_t)28 << 20));     // 0.5MB
  float*          c1   = (float*)(ws + ((size_t)29 << 20));              // 64KB
  float*          c2   = (float*)(ws + ((size_t)29 << 20) + (1 << 16));  // 64KB
  unsigned short* c1bf = (unsigned short*)(ws + ((size_t)29 << 20) + (2 << 16)); // 32KB
  unsigned short* c2bf = (unsigned short*)(ws + ((size_t)29 << 20) + (3 << 16)); // 32KB

  // prep
  tobf_kernel<<<256, 256, 0, stream>>>(states, Sbf);
  w2h_kernel<<<dim3(16, 16), 256, 0, stream>>>(Wi2, W2h);
  uvh_kernel<<<256, 256, 0, stream>>>(states, Wi1, bi1, Uh, Vh);

  // quantum features: qf = tanh(states @ Wq + bq)   K=8192 N=8192, KS=16, L=512
  gemmw<<<dim3(64, 16), 256, 0, stream>>>(Sbf, Wq, P, 8192, 8192, 512, 7);
  reduce_kernel<<<1024, 256, 0, stream>>>(P, bq, qf, qfbf, 13, 16, 2, 1);

  // interactions
  inter4_kernel<<<dim3(4, 64), 512, 0, stream>>>(Uh, Vh, W2h, bi2, Hsum);
  k3_kernel<<<128, 256, 0, stream>>>(Hsum, Wi3, bi3, inter);

  // coordination chain
  // c1 = relu(qf @ Wc1 + bc1): K=8192, N=512, L=128, KS=64
  gemmw<<<dim3(4, 64), 256, 0, stream>>>(qfbf, Wc1, P, 8192, 512, 128, 5);
  reduce_kernel<<<64, 256, 0, stream>>>(P, bc1, c1, c1bf, 9, 64, 1, 1);
  // c2 = relu(c1 @ Wc2 + bc2): K=512, N=512, L=16, KS=32
  gemmw<<<dim3(4, 32), 256, 0, stream>>>(c1bf, Wc2, P, 512, 512, 16, 2);
  reduce_kernel<<<64, 256, 0, stream>>>(P, bc2, c2, c2bf, 9, 32, 1, 1);
  // coord = c2 @ Wc3 + bc3: K=512, N=8192, L=64, KS=8
  gemmw<<<dim3(64, 8), 256, 0, stream>>>(c2bf, Wc3, P, 512, 8192, 64, 4);
  reduce_kernel<<<1024, 256, 0, stream>>>(P, bc3, coord, qfbf, 13, 8, 0, 0);

  // final
  combine_kernel<<<256, 256, 0, stream>>>(states, inter, coord, out0);
}

// Round 9
// 240.603 us; speedup vs baseline: 2.1824x; 1.0444x over previous
//
#include <hip/hip_runtime.h>

typedef __attribute__((ext_vector_type(8))) short bf16x8;
typedef __attribute__((ext_vector_type(16))) float f32x16;
typedef _Float16 f16;
typedef __attribute__((ext_vector_type(8))) _Float16 f16x8;

static __device__ __forceinline__ unsigned short f2bf(float x) {
  unsigned int u = __float_as_uint(x);
  return (unsigned short)((u + 0x7FFFu + ((u >> 16) & 1u)) >> 16);
}
static __device__ __forceinline__ unsigned int pk2bf(float lo, float hi) {
  return ((unsigned int)f2bf(hi) << 16) | f2bf(lo);
}

static __device__ __forceinline__ f16x8 relu8(f16x8 x) {
  f16x8 z = {0, 0, 0, 0, 0, 0, 0, 0};
  return __builtin_elementwise_max(x, z);
}

// ---------------- f32 -> bf16 bulk convert ----------------
__global__ __launch_bounds__(256) void tobf_kernel(const float* __restrict__ src,
                                                   unsigned short* __restrict__ dst) {
  const int idx = blockIdx.x * 256 + threadIdx.x;
  float4 v = ((const float4*)src)[idx];
  ushort4 o;
  o.x = f2bf(v.x); o.y = f2bf(v.y); o.z = f2bf(v.z); o.w = f2bf(v.w);
  ((ushort4*)dst)[idx] = o;
}

// ---------------- Wi2 (512x512 f32) -> W2h f16 transposed [n][k] ----------------
__global__ __launch_bounds__(256) void w2h_kernel(const float* __restrict__ Wi2,
                                                  f16* __restrict__ W2h) {
  __shared__ float tile[32][33];
  const int t = threadIdx.x;
  const int bk = blockIdx.x, bn = blockIdx.y;
  const int r = t >> 5, c = t & 31;
#pragma unroll
  for (int p = 0; p < 4; p++) {
    int rr = p * 8 + r;
    tile[rr][c] = Wi2[(bk * 32 + rr) * 512 + bn * 32 + c];
  }
  __syncthreads();
#pragma unroll
  for (int p = 0; p < 4; p++) {
    int rr = p * 8 + r;
    W2h[(bn * 32 + rr) * 512 + bk * 32 + c] = (f16)tile[c][rr];
  }
}

// ---------------- Uh = f16(S @ Wi1[0:128] + bi1), Vh = f16(S @ Wi1[128:256]) ----------------
__global__ __launch_bounds__(256) void uvh_kernel(const float* __restrict__ S,
                                                  const float* __restrict__ Wi1,
                                                  const float* __restrict__ bi1,
                                                  f16* __restrict__ Uh, f16* __restrict__ Vh) {
  __shared__ float st[128][12];
  const int t = threadIdx.x;
  const int row0 = blockIdx.x * 8;
  for (int idx = t; idx < 1024; idx += 256) {
    int r = idx >> 7, k = idx & 127;
    st[k][r] = S[(row0 + r) * 128 + k];
  }
  __syncthreads();
  float au0[8], au1[8], av0[8], av1[8];
#pragma unroll
  for (int r = 0; r < 8; r++) { au0[r] = 0.f; au1[r] = 0.f; av0[r] = 0.f; av1[r] = 0.f; }
#pragma unroll 4
  for (int k = 0; k < 128; k++) {
    float wt0 = Wi1[k * 512 + t];
    float wt1 = Wi1[k * 512 + 256 + t];
    float wb0 = Wi1[(k + 128) * 512 + t];
    float wb1 = Wi1[(k + 128) * 512 + 256 + t];
    float4 sA = *(const float4*)&st[k][0];
    float4 sB = *(const float4*)&st[k][4];
    float s8[8] = {sA.x, sA.y, sA.z, sA.w, sB.x, sB.y, sB.z, sB.w};
#pragma unroll
    for (int r = 0; r < 8; r++) {
      au0[r] += s8[r] * wt0;
      au1[r] += s8[r] * wt1;
      av0[r] += s8[r] * wb0;
      av1[r] += s8[r] * wb1;
    }
  }
  const float b0 = bi1[t], b1 = bi1[256 + t];
#pragma unroll
  for (int r = 0; r < 8; r++) {
    Uh[(row0 + r) * 512 + t]       = (f16)(au0[r] + b0);
    Uh[(row0 + r) * 512 + 256 + t] = (f16)(au1[r] + b1);
    Vh[(row0 + r) * 512 + t]       = (f16)av0[r];
    Vh[(row0 + r) * 512 + 256 + t] = (f16)av1[r];
  }
}

// ---------------- MFMA M=32 weight-streaming GEMM: P[ks] = Abf[32xK] @ W[k0:k0+L, :] ----------------
__global__ __launch_bounds__(256, 4) void gemmw(const unsigned short* __restrict__ Abf,
                                                const float* __restrict__ W,
                                                float* __restrict__ P,
                                                int K, int N, int L, int l4sh) {
  __shared__ __align__(16) unsigned short As[32 * 512];
  const int t = threadIdx.x;
  const int k0 = blockIdx.y * L;
  const int L4 = L >> 2;
  const int swzm = 2 * L - 1;
  for (int idx = t; idx < (L << 3); idx += 256) {
    int row = idx >> l4sh, k4 = idx & (L4 - 1);
    ushort4 a4 = *(const ushort4*)&Abf[(size_t)row * K + k0 + k4 * 4];
    int off = (row * 2 * L + k4 * 8) ^ (((row & 7) << 4) & swzm);
    *(ushort4*)((char*)As + off) = a4;
  }
  __syncthreads();
  const int lane = t & 63, w = t >> 6;
  const int lrow = lane & 31, lh = lane >> 5;
  const int col = blockIdx.x * 128 + w * 32 + lrow;
  f32x16 acc0, acc1;
#pragma unroll
  for (int r = 0; r < 16; r++) { acc0[r] = 0.f; acc1[r] = 0.f; }
  const float* Wp = W + (size_t)(k0 + lh * 8) * N + col;
  const int aswz = ((lrow & 7) << 4) & swzm;
  const int abase = lrow * 2 * L + lh * 16;
  const int nks = L >> 4;
  int ks = 0;
  for (; ks + 1 < nks; ks += 2) {
    float wv0[8], wv1[8];
#pragma unroll
    for (int jj = 0; jj < 8; jj++) wv0[jj] = Wp[(size_t)(ks * 16 + jj) * N];
#pragma unroll
    for (int jj = 0; jj < 8; jj++) wv1[jj] = Wp[(size_t)(ks * 16 + 16 + jj) * N];
    uint4 b0, b1;
    b0.x = pk2bf(wv0[0], wv0[1]); b0.y = pk2bf(wv0[2], wv0[3]);
    b0.z = pk2bf(wv0[4], wv0[5]); b0.w = pk2bf(wv0[6], wv0[7]);
    b1.x = pk2bf(wv1[0], wv1[1]); b1.y = pk2bf(wv1[2], wv1[3]);
    b1.z = pk2bf(wv1[4], wv1[5]); b1.w = pk2bf(wv1[6], wv1[7]);
    bf16x8 af0 = *(const bf16x8*)((const char*)As + ((abase + ks * 32) ^ aswz));
    bf16x8 af1 = *(const bf16x8*)((const char*)As + ((abase + ks * 32 + 32) ^ aswz));
    acc0 = __builtin_amdgcn_mfma_f32_32x32x16_bf16(af0, *(const bf16x8*)&b0, acc0, 0, 0, 0);
    acc1 = __builtin_amdgcn_mfma_f32_32x32x16_bf16(af1, *(const bf16x8*)&b1, acc1, 0, 0, 0);
  }
  if (ks < nks) {
    float wv0[8];
#pragma unroll
    for (int jj = 0; jj < 8; jj++) wv0[jj] = Wp[(size_t)(ks * 16 + jj) * N];
    uint4 b0;
    b0.x = pk2bf(wv0[0], wv0[1]); b0.y = pk2bf(wv0[2], wv0[3]);
    b0.z = pk2bf(wv0[4], wv0[5]); b0.w = pk2bf(wv0[6], wv0[7]);
    bf16x8 af0 = *(const bf16x8*)((const char*)As + ((abase + ks * 32) ^ aswz));
    acc0 = __builtin_amdgcn_mfma_f32_32x32x16_bf16(af0, *(const bf16x8*)&b0, acc0, 0, 0, 0);
  }
  float* Pr = P + (size_t)blockIdx.y * 32 * N + col;
#pragma unroll
  for (int r = 0; r < 16; r++) {
    int row = (r & 3) + 8 * (r >> 2) + 4 * lh;
    Pr[(size_t)row * N] = acc0[r] + acc1[r];
  }
}

// ---------------- reduce partials + bias + activation (+ optional bf16 copy) ----------------
__global__ __launch_bounds__(256) void reduce_kernel(const float* __restrict__ P,
                                                     const float* __restrict__ bias,
                                                     float* __restrict__ dst,
                                                     unsigned short* __restrict__ dstbf,
                                                     int lnN, int KS, int act, int wbf) {
  const int idx = blockIdx.x * 256 + threadIdx.x;
  const int N = 1 << lnN;
  const int m = idx >> lnN, n = idx & (N - 1);
  float s = 0.f;
#pragma unroll 8
  for (int p = 0; p < KS; p++) s += P[((size_t)(p * 32 + m) << lnN) + n];
  s += bias[n];
  if (act == 1) s = fmaxf(s, 0.f);
  else if (act == 2) s = tanhf(s);
  dst[idx] = s;
  if (wbf) dstbf[idx] = f2bf(s);
}

// ---------------- interaction core v5b: one ii per wave, 2m x 4n frags (swizzle applied at use) ----------------
// Hsum[b,i,:] = sum_{j!=i} relu( relu(Uh[b,i]+Vh[b,j]) @ Wi2 + bi2 )
// grid (4 nq, 64); block 512 = 8 waves = (ii 0..1) x (tg 0..3). Per wave: 2 m-frags (64 j) x 4 n-frags (128 cols).
__global__ __launch_bounds__(512, 2) void inter5_kernel(const f16* __restrict__ Uh,
                                                        const f16* __restrict__ Vh,
                                                        const f16* __restrict__ W2h,
                                                        const float* __restrict__ bi2,
                                                        float* __restrict__ Hsum) {
  __shared__ __align__(16) f16 Bt[128 * 512]; // 128KB, swizzled
  const int t = threadIdx.x;
  const int nq = blockIdx.x;

  // stage B slice once: rows nq*128..+128 of W2h [n][k]
#pragma unroll
  for (int i = 0; i < 16; i++) {
    int idx = i * 512 + t;
    int n = idx >> 6, ch = idx & 63;
    f16x8 w8 = *(const f16x8*)&W2h[(size_t)(nq * 128 + n) * 512 + ch * 8];
    int off = (n * 1024 + ch * 16) ^ ((n & 15) << 4);
    *(f16x8*)((char*)Bt + off) = w8;
  }
  __syncthreads();

  const int w = t >> 6, lane = t & 63;
  const int ii = w & 1, tg = w >> 1;
  const int lrow = lane & 31, lh = lane >> 5;
  const char* Btc = (const char*)Bt;

  int bofs[4], bswz[4];
#pragma unroll
  for (int nf = 0; nf < 4; nf++) {
    int nr = nf * 32 + lrow;
    bofs[nf] = nr * 1024 + lh * 16;   // un-swizzled byte offset
    bswz[nf] = (nr & 15) << 4;        // XOR applied at each use (after +k)
  }

  for (int s = 0; s < 4; s++) {
    const int tid = blockIdx.y * 16 + tg * 4 + s;
    const int b = tid >> 5, it = tid & 31;
    const f16* Vb0 = Vh + (size_t)(b * 64 + lrow) * 512 + lh * 8;
    const f16* Vb1 = Vb0 + (size_t)32 * 512;
    const f16* Ub = Uh + (size_t)(b * 64 + it * 2 + ii) * 512 + lh * 8;

    f32x16 acc[2][4];
#pragma unroll
    for (int mf = 0; mf < 2; mf++)
#pragma unroll
      for (int nf = 0; nf < 4; nf++)
#pragma unroll
        for (int r = 0; r < 16; r++) acc[mf][nf][r] = 0.f;

    f16x8 v0 = *(const f16x8*)(Vb0);
    f16x8 v1 = *(const f16x8*)(Vb1);
    f16x8 u0 = *(const f16x8*)(Ub);
    f16x8 bf[4];
#pragma unroll
    for (int nf = 0; nf < 4; nf++) bf[nf] = *(const f16x8*)(Btc + (bofs[nf] ^ bswz[nf]));

#pragma unroll 2
    for (int kc = 0; kc < 512; kc += 16) {
      const int kn = (kc + 16) & 511;
      // prefetch next k-step
      f16x8 v0n = *(const f16x8*)(Vb0 + kn);
      f16x8 v1n = *(const f16x8*)(Vb1 + kn);
      f16x8 u0n = *(const f16x8*)(Ub + kn);
      f16x8 bfn[4];
#pragma unroll
      for (int nf = 0; nf < 4; nf++)
        bfn[nf] = *(const f16x8*)(Btc + ((bofs[nf] + kn * 2) ^ bswz[nf]));
      // A-frags in registers (lane = j-row, lh = k-half)
      f16x8 a0 = relu8(v0 + u0);   // j 0..31
      f16x8 a1 = relu8(v1 + u0);   // j 32..63
#pragma unroll
      for (int nf = 0; nf < 4; nf++) {
        acc[0][nf] = __builtin_amdgcn_mfma_f32_32x32x16_f16(a0, bf[nf], acc[0][nf], 0, 0, 0);
        acc[1][nf] = __builtin_amdgcn_mfma_f32_32x32x16_f16(a1, bf[nf], acc[1][nf], 0, 0, 0);
      }
      v0 = v0n; v1 = v1n; u0 = u0n;
#pragma unroll
      for (int nf = 0; nf < 4; nf++) bf[nf] = bfn[nf];
    }

    // epilogue: relu(+bi2), sum over 64 j excluding j == iglob, write Hsum
    const int iglob = it * 2 + ii;
    const int mf_d = iglob >> 5;
    const int rd = iglob & 31;
    const int lh_d = (rd >> 2) & 1;
    const int r_d = (rd & 3) + 4 * (rd >> 3);
#pragma unroll
    for (int nf = 0; nf < 4; nf++) {
      const int col = nq * 128 + nf * 32 + lrow;
      const float b2 = bi2[col];
      float ssum = 0.f;
#pragma unroll
      for (int mf = 0; mf < 2; mf++)
#pragma unroll
        for (int r = 0; r < 16; r++) {
          float x = fmaxf(acc[mf][nf][r] + b2, 0.f);
          if (mf == mf_d && r == r_d && lh == lh_d) x = 0.f;
          ssum += x;
        }
      ssum += __shfl_xor(ssum, 32);
      if (lh == 0) Hsum[(size_t)(b * 64 + iglob) * 512 + col] = ssum;
    }
  }
}

// ---------------- interactions = (Hsum/63) @ Wi3 + bi3   (2048x512 @ 512x128) ----------------
__global__ __launch_bounds__(256) void k3_kernel(const float* __restrict__ Hsum,
                                                 const float* __restrict__ Wi3,
                                                 const float* __restrict__ bi3,
                                                 float* __restrict__ inter) {
  __shared__ float st[512][20];
  const int t = threadIdx.x;
  const int row0 = blockIdx.x * 16;
  for (int idx = t; idx < 8192; idx += 256) {
    int r = idx >> 9, k = idx & 511;
    st[k][r] = Hsum[(row0 + r) * 512 + k] * (1.0f / 63.0f);
  }
  __syncthreads();
  const int c = t & 63;
  const int rg = t >> 6;
  float a0[4] = {0.f, 0.f, 0.f, 0.f}, a1[4] = {0.f, 0.f, 0.f, 0.f};
#pragma unroll 4
  for (int k = 0; k < 512; k++) {
    float w0 = Wi3[k * 128 + c];
    float w1 = Wi3[k * 128 + 64 + c];
    float4 h = *(const float4*)&st[k][rg * 4];
    a0[0] += h.x * w0; a0[1] += h.y * w0; a0[2] += h.z * w0; a0[3] += h.w * w0;
    a1[0] += h.x * w1; a1[1] += h.y * w1; a1[2] += h.z * w1; a1[3] += h.w * w1;
  }
  float b0 = bi3[c], b1 = bi3[64 + c];
#pragma unroll
  for (int r = 0; r < 4; r++) {
    inter[(row0 + rg * 4 + r) * 128 + c]      = a0[r] + b0;
    inter[(row0 + rg * 4 + r) * 128 + 64 + c] = a1[r] + b1;
  }
}

// ---------------- final combine ----------------
__global__ __launch_bounds__(256) void combine_kernel(const float* __restrict__ S,
                                                      const float* __restrict__ inter,
                                                      const float* __restrict__ coord,
                                                      float* __restrict__ out0) {
  const int i = blockIdx.x * 256 + threadIdx.x;
  float4 s = ((const float4*)S)[i];
  float4 a = ((const float4*)inter)[i];
  float4 c = ((const float4*)coord)[i];
  float4 o;
  o.x = s.x + 0.1f * (a.x + c.x);
  o.y = s.y + 0.1f * (a.y + c.y);
  o.z = s.z + 0.1f * (a.z + c.z);
  o.w = s.w + 0.1f * (a.w + c.w);
  ((float4*)out0)[i] = o;
}

extern "C" void kernel_launch(void* const* d_in, const int* in_sizes, int n_in,
                              void* d_out, int out_size, void* d_ws, size_t ws_size,
                              hipStream_t stream) {
  const float* states = (const float*)d_in[0];
  const float* Wq  = (const float*)d_in[2];
  const float* bq  = (const float*)d_in[3];
  const float* Wi1 = (const float*)d_in[4];
  const float* bi1 = (const float*)d_in[5];
  const float* Wi2 = (const float*)d_in[6];
  const float* bi2 = (const float*)d_in[7];
  const float* Wi3 = (const float*)d_in[8];
  const float* bi3 = (const float*)d_in[9];
  const float* Wc1 = (const float*)d_in[10];
  const float* bc1 = (const float*)d_in[11];
  const float* Wc2 = (const float*)d_in[12];
  const float* bc2 = (const float*)d_in[13];
  const float* Wc3 = (const float*)d_in[14];
  const float* bc3 = (const float*)d_in[15];

  float* out   = (float*)d_out;
  float* out0  = out;            // coordinated_states (B,A,D)
  float* qf    = out + 262144;   // quantum_features (B,F)
  float* inter = out + 524288;   // interactions (B,A,D)
  float* coord = out + 786432;   // coordination (B,A,D)

  char* ws = (char*)d_ws;
  float*          P    = (float*)(ws);                                   // 16MB partials
  f16*            Uh   = (f16*)(ws + ((size_t)16 << 20));                // 2MB (+pad)
  f16*            Vh   = (f16*)(ws + ((size_t)19 << 20));                // 2MB (+pad)
  f16*            W2h  = (f16*)(ws + ((size_t)22 << 20));                // 0.5MB
  float*          Hsum = (float*)(ws + ((size_t)23 << 20));              // 4MB
  unsigned short* Sbf  = (unsigned short*)(ws + ((size_t)27 << 20));     // 0.5MB
  unsigned short* qfbf = (unsigned short*)(ws + ((size_t)28 << 20));     // 0.5MB
  float*          c1   = (float*)(ws + ((size_t)29 << 20));              // 64KB
  float*          c2   = (float*)(ws + ((size_t)29 << 20) + (1 << 16));  // 64KB
  unsigned short* c1bf = (unsigned short*)(ws + ((size_t)29 << 20) + (2 << 16)); // 32KB
  unsigned short* c2bf = (unsigned short*)(ws + ((size_t)29 << 20) + (3 << 16)); // 32KB

  // prep
  tobf_kernel<<<256, 256, 0, stream>>>(states, Sbf);
  w2h_kernel<<<dim3(16, 16), 256, 0, stream>>>(Wi2, W2h);
  uvh_kernel<<<256, 256, 0, stream>>>(states, Wi1, bi1, Uh, Vh);

  // quantum features: qf = tanh(states @ Wq + bq)   K=8192 N=8192, KS=16, L=512
  gemmw<<<dim3(64, 16), 256, 0, stream>>>(Sbf, Wq, P, 8192, 8192, 512, 7);
  reduce_kernel<<<1024, 256, 0, stream>>>(P, bq, qf, qfbf, 13, 16, 2, 1);

  // interactions
  inter5_kernel<<<dim3(4, 64), 512, 0, stream>>>(Uh, Vh, W2h, bi2, Hsum);
  k3_kernel<<<128, 256, 0, stream>>>(Hsum, Wi3, bi3, inter);

  // coordination chain
  // c1 = relu(qf @ Wc1 + bc1): K=8192, N=512, L=128, KS=64
  gemmw<<<dim3(4, 64), 256, 0, stream>>>(qfbf, Wc1, P, 8192, 512, 128, 5);
  reduce_kernel<<<64, 256, 0, stream>>>(P, bc1, c1, c1bf, 9, 64, 1, 1);
  // c2 = relu(c1 @ Wc2 + bc2): K=512, N=512, L=16, KS=32
  gemmw<<<dim3(4, 32), 256, 0, stream>>>(c1bf, Wc2, P, 512, 512, 16, 2);
  reduce_kernel<<<64, 256, 0, stream>>>(P, bc2, c2, c2bf, 9, 32, 1, 1);
  // coord = c2 @ Wc3 + bc3: K=512, N=8192, L=64, KS=8
  gemmw<<<dim3(64, 8), 256, 0, stream>>>(c2bf, Wc3, P, 512, 8192, 64, 4);
  reduce_kernel<<<1024, 256, 0, stream>>>(P, bc3, coord, qfbf, 13, 8, 0, 0);

  // final
  combine_kernel<<<256, 256, 0, stream>>>(states, inter, coord, out0);
}

// Round 10
// 225.616 us; speedup vs baseline: 2.3274x; 1.0664x over previous
//
#include <hip/hip_runtime.h>

typedef __attribute__((ext_vector_type(8))) short bf16x8;
typedef __attribute__((ext_vector_type(16))) float f32x16;
typedef _Float16 f16;
typedef __attribute__((ext_vector_type(8))) _Float16 f16x8;

static __device__ __forceinline__ unsigned short f2bf(float x) {
  unsigned int u = __float_as_uint(x);
  return (unsigned short)((u + 0x7FFFu + ((u >> 16) & 1u)) >> 16);
}
static __device__ __forceinline__ unsigned int pk2bf(float lo, float hi) {
  return ((unsigned int)f2bf(hi) << 16) | f2bf(lo);
}

static __device__ __forceinline__ f16x8 relu8(f16x8 x) {
  f16x8 z = {0, 0, 0, 0, 0, 0, 0, 0};
  return __builtin_elementwise_max(x, z);
}

// ---------------- f32 -> bf16 bulk convert ----------------
__global__ __launch_bounds__(256) void tobf_kernel(const float* __restrict__ src,
                                                   unsigned short* __restrict__ dst) {
  const int idx = blockIdx.x * 256 + threadIdx.x;
  float4 v = ((const float4*)src)[idx];
  ushort4 o;
  o.x = f2bf(v.x); o.y = f2bf(v.y); o.z = f2bf(v.z); o.w = f2bf(v.w);
  ((ushort4*)dst)[idx] = o;
}

// ---------------- Wi2 (512x512 f32) -> W2h f16 transposed [n][k] ----------------
__global__ __launch_bounds__(256) void w2h_kernel(const float* __restrict__ Wi2,
                                                  f16* __restrict__ W2h) {
  __shared__ float tile[32][33];
  const int t = threadIdx.x;
  const int bk = blockIdx.x, bn = blockIdx.y;
  const int r = t >> 5, c = t & 31;
#pragma unroll
  for (int p = 0; p < 4; p++) {
    int rr = p * 8 + r;
    tile[rr][c] = Wi2[(bk * 32 + rr) * 512 + bn * 32 + c];
  }
  __syncthreads();
#pragma unroll
  for (int p = 0; p < 4; p++) {
    int rr = p * 8 + r;
    W2h[(bn * 32 + rr) * 512 + bk * 32 + c] = (f16)tile[c][rr];
  }
}

// ---------------- Uh = f16(S @ Wi1[0:128] + bi1), Vh = f16(S @ Wi1[128:256]) ----------------
__global__ __launch_bounds__(256) void uvh_kernel(const float* __restrict__ S,
                                                  const float* __restrict__ Wi1,
                                                  const float* __restrict__ bi1,
                                                  f16* __restrict__ Uh, f16* __restrict__ Vh) {
  __shared__ float st[128][12];
  const int t = threadIdx.x;
  const int row0 = blockIdx.x * 8;
  for (int idx = t; idx < 1024; idx += 256) {
    int r = idx >> 7, k = idx & 127;
    st[k][r] = S[(row0 + r) * 128 + k];
  }
  __syncthreads();
  float au0[8], au1[8], av0[8], av1[8];
#pragma unroll
  for (int r = 0; r < 8; r++) { au0[r] = 0.f; au1[r] = 0.f; av0[r] = 0.f; av1[r] = 0.f; }
#pragma unroll 4
  for (int k = 0; k < 128; k++) {
    float wt0 = Wi1[k * 512 + t];
    float wt1 = Wi1[k * 512 + 256 + t];
    float wb0 = Wi1[(k + 128) * 512 + t];
    float wb1 = Wi1[(k + 128) * 512 + 256 + t];
    float4 sA = *(const float4*)&st[k][0];
    float4 sB = *(const float4*)&st[k][4];
    float s8[8] = {sA.x, sA.y, sA.z, sA.w, sB.x, sB.y, sB.z, sB.w};
#pragma unroll
    for (int r = 0; r < 8; r++) {
      au0[r] += s8[r] * wt0;
      au1[r] += s8[r] * wt1;
      av0[r] += s8[r] * wb0;
      av1[r] += s8[r] * wb1;
    }
  }
  const float b0 = bi1[t], b1 = bi1[256 + t];
#pragma unroll
  for (int r = 0; r < 8; r++) {
    Uh[(row0 + r) * 512 + t]       = (f16)(au0[r] + b0);
    Uh[(row0 + r) * 512 + 256 + t] = (f16)(au1[r] + b1);
    Vh[(row0 + r) * 512 + t]       = (f16)av0[r];
    Vh[(row0 + r) * 512 + 256 + t] = (f16)av1[r];
  }
}

// ---------------- MFMA M=32 weight-streaming GEMM: P[ks] = Abf[32xK] @ W[k0:k0+L, :] ----------------
__global__ __launch_bounds__(256, 4) void gemmw(const unsigned short* __restrict__ Abf,
                                                const float* __restrict__ W,
                                                float* __restrict__ P,
                                                int K, int N, int L, int l4sh) {
  __shared__ __align__(16) unsigned short As[32 * 512];
  const int t = threadIdx.x;
  const int k0 = blockIdx.y * L;
  const int L4 = L >> 2;
  const int swzm = 2 * L - 1;
  for (int idx = t; idx < (L << 3); idx += 256) {
    int row = idx >> l4sh, k4 = idx & (L4 - 1);
    ushort4 a4 = *(const ushort4*)&Abf[(size_t)row * K + k0 + k4 * 4];
    int off = (row * 2 * L + k4 * 8) ^ (((row & 7) << 4) & swzm);
    *(ushort4*)((char*)As + off) = a4;
  }
  __syncthreads();
  const int lane = t & 63, w = t >> 6;
  const int lrow = lane & 31, lh = lane >> 5;
  const int col = blockIdx.x * 128 + w * 32 + lrow;
  f32x16 acc0, acc1;
#pragma unroll
  for (int r = 0; r < 16; r++) { acc0[r] = 0.f; acc1[r] = 0.f; }
  const float* Wp = W + (size_t)(k0 + lh * 8) * N + col;
  const int aswz = ((lrow & 7) << 4) & swzm;
  const int abase = lrow * 2 * L + lh * 16;
  const int nks = L >> 4;
  int ks = 0;
  for (; ks + 1 < nks; ks += 2) {
    float wv0[8], wv1[8];
#pragma unroll
    for (int jj = 0; jj < 8; jj++) wv0[jj] = Wp[(size_t)(ks * 16 + jj) * N];
#pragma unroll
    for (int jj = 0; jj < 8; jj++) wv1[jj] = Wp[(size_t)(ks * 16 + 16 + jj) * N];
    uint4 b0, b1;
    b0.x = pk2bf(wv0[0], wv0[1]); b0.y = pk2bf(wv0[2], wv0[3]);
    b0.z = pk2bf(wv0[4], wv0[5]); b0.w = pk2bf(wv0[6], wv0[7]);
    b1.x = pk2bf(wv1[0], wv1[1]); b1.y = pk2bf(wv1[2], wv1[3]);
    b1.z = pk2bf(wv1[4], wv1[5]); b1.w = pk2bf(wv1[6], wv1[7]);
    bf16x8 af0 = *(const bf16x8*)((const char*)As + ((abase + ks * 32) ^ aswz));
    bf16x8 af1 = *(const bf16x8*)((const char*)As + ((abase + ks * 32 + 32) ^ aswz));
    acc0 = __builtin_amdgcn_mfma_f32_32x32x16_bf16(af0, *(const bf16x8*)&b0, acc0, 0, 0, 0);
    acc1 = __builtin_amdgcn_mfma_f32_32x32x16_bf16(af1, *(const bf16x8*)&b1, acc1, 0, 0, 0);
  }
  if (ks < nks) {
    float wv0[8];
#pragma unroll
    for (int jj = 0; jj < 8; jj++) wv0[jj] = Wp[(size_t)(ks * 16 + jj) * N];
    uint4 b0;
    b0.x = pk2bf(wv0[0], wv0[1]); b0.y = pk2bf(wv0[2], wv0[3]);
    b0.z = pk2bf(wv0[4], wv0[5]); b0.w = pk2bf(wv0[6], wv0[7]);
    bf16x8 af0 = *(const bf16x8*)((const char*)As + ((abase + ks * 32) ^ aswz));
    acc0 = __builtin_amdgcn_mfma_f32_32x32x16_bf16(af0, *(const bf16x8*)&b0, acc0, 0, 0, 0);
  }
  float* Pr = P + (size_t)blockIdx.y * 32 * N + col;
#pragma unroll
  for (int r = 0; r < 16; r++) {
    int row = (r & 3) + 8 * (r >> 2) + 4 * lh;
    Pr[(size_t)row * N] = acc0[r] + acc1[r];
  }
}

// ---------------- reduce partials + bias + activation (+ optional bf16 copy) ----------------
__global__ __launch_bounds__(256) void reduce_kernel(const float* __restrict__ P,
                                                     const float* __restrict__ bias,
                                                     float* __restrict__ dst,
                                                     unsigned short* __restrict__ dstbf,
                                                     int lnN, int KS, int act, int wbf) {
  const int idx = blockIdx.x * 256 + threadIdx.x;
  const int N = 1 << lnN;
  const int m = idx >> lnN, n = idx & (N - 1);
  float s = 0.f;
#pragma unroll 8
  for (int p = 0; p < KS; p++) s += P[((size_t)(p * 32 + m) << lnN) + n];
  s += bias[n];
  if (act == 1) s = fmaxf(s, 0.f);
  else if (act == 2) s = tanhf(s);
  dst[idx] = s;
  if (wbf) dstbf[idx] = f2bf(s);
}

// ---------------- interaction core v6: V via LDS (kills 64-lane gather), persistent-B ----------------
// Hsum[b,i,:] = sum_{j!=i} relu( relu(Uh[b,i]+Vh[b,j]) @ Wi2 + bi2 )
// grid (4 nq, 64); block 512 = 8 waves = (ii 0..1) x (tg 0..3). Per wave: 2 m-frags x 4 n-frags.
// LDS: Bt 128KB persistent + Vc 16KB per-128k-chunk (coalesced stage, XOR-swizzled).
__global__ __launch_bounds__(512, 2) void inter6_kernel(const f16* __restrict__ Uh,
                                                        const f16* __restrict__ Vh,
                                                        const f16* __restrict__ W2h,
                                                        const float* __restrict__ bi2,
                                                        float* __restrict__ Hsum) {
  __shared__ __align__(16) f16 Bt[128 * 512]; // 128KB
  __shared__ __align__(16) f16 Vc[64 * 128];  // 16KB chunk of V
  const int t = threadIdx.x;
  const int nq = blockIdx.x;

  // stage B slice once: rows nq*128..+128 of W2h [n][k]
#pragma unroll
  for (int i = 0; i < 16; i++) {
    int idx = i * 512 + t;
    int n = idx >> 6, ch = idx & 63;
    f16x8 w8 = *(const f16x8*)&W2h[(size_t)(nq * 128 + n) * 512 + ch * 8];
    int off = (n * 1024 + ch * 16) ^ ((n & 15) << 4);
    *(f16x8*)((char*)Bt + off) = w8;
  }

  const int w = t >> 6, lane = t & 63;
  const int ii = w & 1, tg = w >> 1;
  const int lrow = lane & 31, lh = lane >> 5;
  const char* Btc = (const char*)Bt;
  const char* Vcc = (const char*)Vc;
  char* Vcw = (char*)Vc;

  int bofs[4], bswz[4];
#pragma unroll
  for (int nf = 0; nf < 4; nf++) {
    int nr = nf * 32 + lrow;
    bofs[nf] = nr * 1024 + lh * 16;   // un-swizzled; XOR applied after +k
    bswz[nf] = (nr & 15) << 4;
  }
  // V read offsets (within chunk): rows lrow and lrow+32, swizzle applied after +k
  const int vofs0 = lrow * 256;
  const int vswz0 = (lrow & 15) << 4;
  const int vofs1 = (lrow + 32) * 256;
  const int vswz1 = vswz0;  // (lrow+32)&15 == lrow&15

  const int b = blockIdx.y >> 1;  // batch (tid = by*16+..., b = tid>>5 = by>>1)

  for (int s = 0; s < 4; s++) {
    const int tid = blockIdx.y * 16 + tg * 4 + s;
    const int it = tid & 31;
    const f16* Ub = Uh + (size_t)(b * 64 + it * 2 + ii) * 512 + lh * 8;

    f32x16 acc[2][4];
#pragma unroll
    for (int mf = 0; mf < 2; mf++)
#pragma unroll
      for (int nf = 0; nf < 4; nf++)
#pragma unroll
        for (int r = 0; r < 16; r++) acc[mf][nf][r] = 0.f;

    for (int ch = 0; ch < 4; ch++) {
      const int kc = ch * 128;
      __syncthreads();
      // ---- stage V chunk: 64 rows x 128 k, coalesced global, swizzled LDS ----
#pragma unroll
      for (int i = 0; i < 2; i++) {
        int idx = i * 512 + t;
        int row = idx >> 4, c8 = idx & 15;
        f16x8 w8 = *(const f16x8*)&Vh[(size_t)(b * 64 + row) * 512 + kc + c8 * 8];
        *(f16x8*)(Vcw + ((row * 256 + c8 * 16) ^ ((row & 15) << 4))) = w8;
      }
      __syncthreads();
      // ---- 8 k-steps of 16 ----
#pragma unroll
      for (int k16 = 0; k16 < 8; k16++) {
        const int kb2 = k16 * 32 + lh * 16;  // byte offset in chunk row
        f16x8 v0 = *(const f16x8*)(Vcc + ((vofs0 + kb2) ^ vswz0));
        f16x8 v1 = *(const f16x8*)(Vcc + ((vofs1 + kb2) ^ vswz1));
        f16x8 u0 = *(const f16x8*)(Ub + kc + k16 * 16);  // wave-uniform broadcast
        f16x8 a0 = relu8(v0 + u0);   // j 0..31
        f16x8 a1 = relu8(v1 + u0);   // j 32..63
        const int kbyte = (kc + k16 * 16) * 2 + lh * 16 - lh * 16; // (kc+k16*16)*2 base; lh folded in bofs
        (void)kbyte;
#pragma unroll
        for (int nf = 0; nf < 4; nf++) {
          f16x8 bfr = *(const f16x8*)(Btc + ((bofs[nf] + (kc + k16 * 16) * 2) ^ bswz[nf]));
          acc[0][nf] = __builtin_amdgcn_mfma_f32_32x32x16_f16(a0, bfr, acc[0][nf], 0, 0, 0);
          acc[1][nf] = __builtin_amdgcn_mfma_f32_32x32x16_f16(a1, bfr, acc[1][nf], 0, 0, 0);
        }
      }
    }

    // ---- epilogue: relu(+bi2), sum over 64 j excluding j == iglob, write ----
    const int iglob = it * 2 + ii;
    const int mf_d = iglob >> 5;
    const int rd = iglob & 31;
    const int lh_d = (rd >> 2) & 1;
    const int r_d = (rd & 3) + 4 * (rd >> 3);
#pragma unroll
    for (int nf = 0; nf < 4; nf++) {
      const int col = nq * 128 + nf * 32 + lrow;
      const float b2 = bi2[col];
      float ssum = 0.f;
#pragma unroll
      for (int mf = 0; mf < 2; mf++)
#pragma unroll
        for (int r = 0; r < 16; r++) {
          float x = fmaxf(acc[mf][nf][r] + b2, 0.f);
          if (mf == mf_d && r == r_d && lh == lh_d) x = 0.f;
          ssum += x;
        }
      ssum += __shfl_xor(ssum, 32);
      if (lh == 0) Hsum[(size_t)(b * 64 + iglob) * 512 + col] = ssum;
    }
  }
}

// ---------------- interactions = (Hsum/63) @ Wi3 + bi3   (2048x512 @ 512x128), 256 blocks ----------------
__global__ __launch_bounds__(256) void k3_kernel(const float* __restrict__ Hsum,
                                                 const float* __restrict__ Wi3,
                                                 const float* __restrict__ bi3,
                                                 float* __restrict__ inter) {
  __shared__ float st[512][10];
  const int t = threadIdx.x;
  const int row0 = blockIdx.x * 8;
  for (int idx = t; idx < 4096; idx += 256) {
    int r = idx >> 9, k = idx & 511;
    st[k][r] = Hsum[(row0 + r) * 512 + k] * (1.0f / 63.0f);
  }
  __syncthreads();
  const int c = t & 63;
  const int rg = t >> 6;
  float a0[2] = {0.f, 0.f}, a1[2] = {0.f, 0.f};
#pragma unroll 4
  for (int k = 0; k < 512; k++) {
    float w0 = Wi3[k * 128 + c];
    float w1 = Wi3[k * 128 + 64 + c];
    float2 h = *(const float2*)&st[k][rg * 2];
    a0[0] += h.x * w0; a0[1] += h.y * w0;
    a1[0] += h.x * w1; a1[1] += h.y * w1;
  }
  float b0 = bi3[c], b1 = bi3[64 + c];
#pragma unroll
  for (int r = 0; r < 2; r++) {
    inter[(row0 + rg * 2 + r) * 128 + c]      = a0[r] + b0;
    inter[(row0 + rg * 2 + r) * 128 + 64 + c] = a1[r] + b1;
  }
}

// ---------------- final combine ----------------
__global__ __launch_bounds__(256) void combine_kernel(const float* __restrict__ S,
                                                      const float* __restrict__ inter,
                                                      const float* __restrict__ coord,
                                                      float* __restrict__ out0) {
  const int i = blockIdx.x * 256 + threadIdx.x;
  float4 s = ((const float4*)S)[i];
  float4 a = ((const float4*)inter)[i];
  float4 c = ((const float4*)coord)[i];
  float4 o;
  o.x = s.x + 0.1f * (a.x + c.x);
  o.y = s.y + 0.1f * (a.y + c.y);
  o.z = s.z + 0.1f * (a.z + c.z);
  o.w = s.w + 0.1f * (a.w + c.w);
  ((float4*)out0)[i] = o;
}

extern "C" void kernel_launch(void* const* d_in, const int* in_sizes, int n_in,
                              void* d_out, int out_size, void* d_ws, size_t ws_size,
                              hipStream_t stream) {
  const float* states = (const float*)d_in[0];
  const float* Wq  = (const float*)d_in[2];
  const float* bq  = (const float*)d_in[3];
  const float* Wi1 = (const float*)d_in[4];
  const float* bi1 = (const float*)d_in[5];
  const float* Wi2 = (const float*)d_in[6];
  const float* bi2 = (const float*)d_in[7];
  const float* Wi3 = (const float*)d_in[8];
  const float* bi3 = (const float*)d_in[9];
  const float* Wc1 = (const float*)d_in[10];
  const float* bc1 = (const float*)d_in[11];
  const float* Wc2 = (const float*)d_in[12];
  const float* bc2 = (const float*)d_in[13];
  const float* Wc3 = (const float*)d_in[14];
  const float* bc3 = (const float*)d_in[15];

  float* out   = (float*)d_out;
  float* out0  = out;            // coordinated_states (B,A,D)
  float* qf    = out + 262144;   // quantum_features (B,F)
  float* inter = out + 524288;   // interactions (B,A,D)
  float* coord = out + 786432;   // coordination (B,A,D)

  char* ws = (char*)d_ws;
  float*          P    = (float*)(ws);                                   // 16MB partials
  f16*            Uh   = (f16*)(ws + ((size_t)16 << 20));                // 2MB (+pad)
  f16*            Vh   = (f16*)(ws + ((size_t)19 << 20));                // 2MB (+pad)
  f16*            W2h  = (f16*)(ws + ((size_t)22 << 20));                // 0.5MB
  float*          Hsum = (float*)(ws + ((size_t)23 << 20));              // 4MB
  unsigned short* Sbf  = (unsigned short*)(ws + ((size_t)27 << 20));     // 0.5MB
  unsigned short* qfbf = (unsigned short*)(ws + ((size_t)28 << 20));     // 0.5MB
  float*          c1   = (float*)(ws + ((size_t)29 << 20));              // 64KB
  float*          c2   = (float*)(ws + ((size_t)29 << 20) + (1 << 16));  // 64KB
  unsigned short* c1bf = (unsigned short*)(ws + ((size_t)29 << 20) + (2 << 16)); // 32KB
  unsigned short* c2bf = (unsigned short*)(ws + ((size_t)29 << 20) + (3 << 16)); // 32KB

  // prep
  tobf_kernel<<<256, 256, 0, stream>>>(states, Sbf);
  w2h_kernel<<<dim3(16, 16), 256, 0, stream>>>(Wi2, W2h);
  uvh_kernel<<<256, 256, 0, stream>>>(states, Wi1, bi1, Uh, Vh);

  // quantum features: qf = tanh(states @ Wq + bq)   K=8192 N=8192, KS=16, L=512
  gemmw<<<dim3(64, 16), 256, 0, stream>>>(Sbf, Wq, P, 8192, 8192, 512, 7);
  reduce_kernel<<<1024, 256, 0, stream>>>(P, bq, qf, qfbf, 13, 16, 2, 1);

  // interactions
  inter6_kernel<<<dim3(4, 64), 512, 0, stream>>>(Uh, Vh, W2h, bi2, Hsum);
  k3_kernel<<<256, 256, 0, stream>>>(Hsum, Wi3, bi3, inter);

  // coordination chain
  // c1 = relu(qf @ Wc1 + bc1): K=8192, N=512, L=128, KS=64
  gemmw<<<dim3(4, 64), 256, 0, stream>>>(qfbf, Wc1, P, 8192, 512, 128, 5);
  reduce_kernel<<<64, 256, 0, stream>>>(P, bc1, c1, c1bf, 9, 64, 1, 1);
  // c2 = relu(c1 @ Wc2 + bc2): K=512, N=512, L=16, KS=32
  gemmw<<<dim3(4, 32), 256, 0, stream>>>(c1bf, Wc2, P, 512, 512, 16, 2);
  reduce_kernel<<<64, 256, 0, stream>>>(P, bc2, c2, c2bf, 9, 32, 1, 1);
  // coord = c2 @ Wc3 + bc3: K=512, N=8192, L=64, KS=8
  gemmw<<<dim3(64, 8), 256, 0, stream>>>(c2bf, Wc3, P, 512, 8192, 64, 4);
  reduce_kernel<<<1024, 256, 0, stream>>>(P, bc3, coord, qfbf, 13, 8, 0, 0);

  // final
  combine_kernel<<<256, 256, 0, stream>>>(states, inter, coord, out0);
}